// Round 12
// baseline (551.975 us; speedup 1.0000x reference)
//
#include <hip/hip_runtime.h>
#include <hip/hip_bf16.h>

constexpr int N    = 8000;
constexpr int E    = 128000;
constexpr int G    = 4;
constexpr int NEL  = 10;
constexpr int NGR  = N / G;          // 2000
constexpr int NC   = N * 64;         // 512000
constexpr int NK   = 342;            // Ewald vectors
constexpr float RMAX = 5.0f;
constexpr int HS = 72;               // padded LDS row stride (bf16) for MFMA tiles
constexpr int WS2 = 260;             // wfull row stride (ushorts)
constexpr int WT_T = 25088;          // per-t size of transposed radial-weight block (ushorts)

typedef __bf16 bf16x8 __attribute__((ext_vector_type(8)));
typedef float  f32x4v __attribute__((ext_vector_type(4)));
typedef unsigned short u16x8 __attribute__((ext_vector_type(8)));

__device__ __forceinline__ int lmap_rt(int l) { return (l >= 1) + (l >= 4) + (l >= 9); }
__device__ __forceinline__ float silu(float x) { return x / (1.f + __expf(-x)); }
__device__ __forceinline__ float bf2f(unsigned short u) { return __uint_as_float(((unsigned)u) << 16); }
__device__ __forceinline__ unsigned short f2bf(float f) {
    __hip_bfloat16 h = __float2bfloat16(f);
    return *(unsigned short*)&h;
}
__device__ __forceinline__ float rdlane(float v, int lane) {
    return __uint_as_float(__builtin_amdgcn_readlane(__float_as_uint(v), lane));
}

// MFMA 64x64(xK) stage: hsrc rows = M (stride HS), wt rows = N (stride HS), K=64 (or 8)
__device__ __forceinline__ void mfma_stage(const unsigned short* hsrc, const unsigned short* wt,
                                           int m0, int lane, f32x4v acc[4], bool k8only)
{
    const int quad = lane >> 4;
    const int idx  = lane & 15;
    bf16x8 bz;
    #pragma unroll
    for (int i = 0; i < 8; ++i) bz[i] = (__bf16)0.f;
    bf16x8 a0 = bz, a1 = bz;
    const int mrow = m0 + idx;
    if (k8only) {
        if (quad == 0) a0 = *(const bf16x8*)&hsrc[mrow * HS];
    } else {
        a0 = *(const bf16x8*)&hsrc[mrow * HS + (quad << 3)];
        a1 = *(const bf16x8*)&hsrc[mrow * HS + 32 + (quad << 3)];
    }
    #pragma unroll
    for (int c4 = 0; c4 < 4; ++c4) {
        const int nrow = (c4 << 4) + idx;
        if (k8only) {
            bf16x8 b0 = bz;
            if (quad == 0) b0 = *(const bf16x8*)&wt[nrow * HS];
            acc[c4] = __builtin_amdgcn_mfma_f32_16x16x32_bf16(a0, b0, acc[c4], 0, 0, 0);
        } else {
            const bf16x8 b0 = *(const bf16x8*)&wt[nrow * HS + (quad << 3)];
            const bf16x8 b1 = *(const bf16x8*)&wt[nrow * HS + 32 + (quad << 3)];
            acc[c4] = __builtin_amdgcn_mfma_f32_16x16x32_bf16(a0, b0, acc[c4], 0, 0, 0);
            acc[c4] = __builtin_amdgcn_mfma_f32_16x16x32_bf16(a1, b1, acc[c4], 0, 0, 0);
        }
    }
}

// ---------------- init: elem, hist, e0/charge/dipole ----------------
__global__ __launch_bounds__(256) void k_init(const float* __restrict__ na,
    const float* __restrict__ q, const float* __restrict__ pos,
    const int* __restrict__ batch, const float* __restrict__ aE,
    int* __restrict__ elem, int* __restrict__ counts, float* __restrict__ acc)
{
    __shared__ float s[G * 5];
    if (threadIdx.x < G * 5) s[threadIdx.x] = 0.f;
    __syncthreads();
    const int n = blockIdx.x * 256 + threadIdx.x;
    if (n < N) {
        int el = 0; float best = na[n * NEL];
        #pragma unroll
        for (int j = 1; j < NEL; ++j) { float v = na[n * NEL + j]; if (v > best) { best = v; el = j; } }
        elem[n] = el;
        atomicAdd(&counts[el], 1);
        const int g = batch[n];
        const float qn = q[n];
        atomicAdd(&s[g * 5 + 0], aE[el]);
        atomicAdd(&s[g * 5 + 1], qn);
        atomicAdd(&s[g * 5 + 2], qn * pos[n * 3 + 0]);
        atomicAdd(&s[g * 5 + 3], qn * pos[n * 3 + 1]);
        atomicAdd(&s[g * 5 + 4], qn * pos[n * 3 + 2]);
    }
    __syncthreads();
    if (threadIdx.x < G * 5) atomicAdd(&acc[threadIdx.x], s[threadIdx.x]);
}

__global__ __launch_bounds__(256) void k_feat0(const int* __restrict__ elem,
    const float* __restrict__ embW, unsigned short* __restrict__ Fb)
{
    const int i = blockIdx.x * 256 + threadIdx.x;
    if (i < NC) Fb[i] = f2bf(embW[elem[i >> 6] * 64 + (i & 63)]);
}

// ---------------- element bucketing ----------------
__global__ void k_offs(const int* __restrict__ counts, int* __restrict__ offs)
{
    if (threadIdx.x == 0 && blockIdx.x == 0) {
        int o = 0;
        for (int j = 0; j < NEL; ++j) { offs[j] = o; o += (counts[j] + 63) & ~63; }
        offs[NEL] = o;
    }
}
__global__ __launch_bounds__(256) void k_scatter(const int* __restrict__ elem,
    const int* __restrict__ offs, int* __restrict__ cursor, int* __restrict__ perm)
{
    const int n = blockIdx.x * 256 + threadIdx.x;
    if (n < N) {
        const int el = elem[n];
        const int p = atomicAdd(&cursor[el], 1);
        perm[offs[el] + p] = n;
    }
}

// ---------------- receiver CSR build ----------------
__global__ __launch_bounds__(256) void k_gcnt(const int* __restrict__ ei, int* __restrict__ cnt)
{
    const int e = blockIdx.x * 256 + threadIdx.x;
    if (e < E) atomicAdd(&cnt[ei[E + e]], 1);
}
__global__ __launch_bounds__(1024) void k_goff(const int* __restrict__ cnt, int* __restrict__ roff)
{
    __shared__ int part[1024];
    const int t = threadIdx.x;
    const int base = t * 8;
    int loc[8];
    int s = 0;
    #pragma unroll
    for (int i = 0; i < 8; ++i) { loc[i] = s; s += (base + i < N) ? cnt[base + i] : 0; }
    part[t] = s;
    __syncthreads();
    for (int d = 1; d < 1024; d <<= 1) {
        const int v = (t >= d) ? part[t - d] : 0;
        __syncthreads();
        part[t] += v;
        __syncthreads();
    }
    const int excl = (t == 0) ? 0 : part[t - 1];
    #pragma unroll
    for (int i = 0; i < 8; ++i) if (base + i < N) roff[base + i] = excl + loc[i];
    if (t == 0) roff[N] = E;
}
__global__ __launch_bounds__(256) void k_gscat(const int* __restrict__ ei,
    const int* __restrict__ roff, int* __restrict__ cur, int* __restrict__ elist)
{
    const int e = blockIdx.x * 256 + threadIdx.x;
    if (e < E) {
        const int rv = ei[E + e];
        const int p = atomicAdd(&cur[rv], 1);
        elist[roff[rv] + p] = e;
    }
}

// ---------------- per-elist-position geometry precompute ----------------
__global__ __launch_bounds__(256) void k_geom(const float* __restrict__ pos,
    const float* __restrict__ shifts, const int* __restrict__ ei,
    const int* __restrict__ elist, float4* __restrict__ geomv, int* __restrict__ spck)
{
    const int j = blockIdx.x * 256 + threadIdx.x;
    if (j >= E) return;
    const int e = elist[j];
    const int s = ei[e], rv = ei[E + e];
    const float dx = pos[rv * 3 + 0] - pos[s * 3 + 0] + shifts[e * 3 + 0];
    const float dy = pos[rv * 3 + 1] - pos[s * 3 + 1] + shifts[e * 3 + 1];
    const float dz = pos[rv * 3 + 2] - pos[s * 3 + 2] + shifts[e * 3 + 2];
    const float r = sqrtf(dx * dx + dy * dy + dz * dz);
    const float inv = 1.f / (r + 1e-9f);
    float4 g;
    g.x = dx * inv; g.y = dy * inv; g.z = dz * inv; g.w = r;
    geomv[j] = g;
    spck[j] = s;
}

// ---------------- merged weight transpose+bf16 prep (runs once) ----------------
__global__ __launch_bounds__(256) void k_wprep_all(const float* __restrict__ rW1,
    const float* __restrict__ rW2, const float* __restrict__ rW3,
    const float* __restrict__ rW4, const float* __restrict__ Wp,
    const float* __restrict__ lup, const float* __restrict__ lout,
    const float* __restrict__ Wsc,
    unsigned short* __restrict__ WT, unsigned short* __restrict__ WpT,
    unsigned short* __restrict__ WlupT, unsigned short* __restrict__ WloutT,
    unsigned short* __restrict__ WscT)
{
    const int gidx = blockIdx.x * 256 + threadIdx.x;
    if (gidx < 2 * WT_T) {
        const int t = gidx / WT_T;
        const int r = gidx % WT_T;
        float v;
        if (r < 512) {
            const int n = r >> 3, k = r & 7;
            v = rW1[t * 512 + k * 64 + n];
        } else if (r < 4608) {
            const int i = r - 512, n = i >> 6, k = i & 63;
            v = rW2[t * 4096 + k * 64 + n];
        } else if (r < 8704) {
            const int i = r - 4608, n = i >> 6, k = i & 63;
            v = rW3[t * 4096 + k * 64 + n];
        } else {
            const int i = r - 8704, n = i >> 6, k = i & 63;
            v = rW4[t * 16384 + k * 256 + n];
        }
        WT[gidx] = f2bf(v);
    } else if (gidx < 2 * WT_T + 24576) {
        const int idx = gidx - 2 * WT_T;
        const int i  = idx & 4095;
        const int d = i >> 6, c = i & 63;
        WpT[idx] = f2bf(Wp[(size_t)(idx >> 12) * 4096 + c * 64 + d]);
    } else if (gidx < 2 * WT_T + 24576 + 32768) {
        const int idx = gidx - (2 * WT_T + 24576);
        const int i = idx & 4095, d = i >> 6, c = i & 63;
        WlupT[idx] = f2bf(lup[(idx >> 12) * 4096 + c * 64 + d]);
    } else if (gidx < 2 * WT_T + 24576 + 65536) {
        const int idx = gidx - (2 * WT_T + 24576 + 32768);
        const int i = idx & 4095, d = i >> 6, c = i & 63;
        WloutT[idx] = f2bf(lout[(idx >> 12) * 4096 + c * 64 + d]);
    } else if (gidx < 2 * WT_T + 24576 + 65536 + 81920) {
        const int idx = gidx - (2 * WT_T + 24576 + 65536);
        const int i = idx & 4095, d = i >> 6, c = i & 63;
        WscT[idx] = f2bf(Wsc[(idx >> 12) * 4096 + c * 64 + d]);
    }
}

// ---------------- lin_up GEMM (MFMA) on bf16 F; l==0 folds q*qc update ----------------
__global__ __launch_bounds__(256) void k_lgemm_hb(unsigned short* __restrict__ Fb,
    const float* __restrict__ q, const float* __restrict__ qc,
    const unsigned short* __restrict__ WT, unsigned short* __restrict__ Hb)
{
    __shared__ unsigned short Xb[64 * HS];
    __shared__ unsigned short Wt[64 * HS];
    const int l  = blockIdx.y;
    const int nb = blockIdx.x << 6;
    const int t  = threadIdx.x;
    const int lane = t & 63;
    const int m0   = (t >> 6) << 4;
    const int quad = lane >> 4;
    const int idx  = lane & 15;
    const int prow = t >> 2, pkb = (t & 3) << 4;
    unsigned short* Xp = Fb + (size_t)l * NC + (size_t)nb * 64;
    if (l == 0) {
        const float qn = q[nb + prow];
        u16x8 x0 = *(const u16x8*)&Xp[prow * 64 + pkb];
        u16x8 x1 = *(const u16x8*)&Xp[prow * 64 + pkb + 8];
        #pragma unroll
        for (int j = 0; j < 8; ++j) {
            x0[j] = f2bf(bf2f(x0[j]) + qn * qc[pkb + j]);
            x1[j] = f2bf(bf2f(x1[j]) + qn * qc[pkb + 8 + j]);
        }
        *(u16x8*)&Xp[prow * 64 + pkb]     = x0;
        *(u16x8*)&Xp[prow * 64 + pkb + 8] = x1;
        *(u16x8*)&Xb[prow * HS + pkb]     = x0;
        *(u16x8*)&Xb[prow * HS + pkb + 8] = x1;
    } else {
        *(u16x8*)&Xb[prow * HS + pkb]     = *(const u16x8*)&Xp[prow * 64 + pkb];
        *(u16x8*)&Xb[prow * HS + pkb + 8] = *(const u16x8*)&Xp[prow * 64 + pkb + 8];
    }
    const unsigned short* W = WT + lmap_rt(l) * 4096;
    *(u16x8*)&Wt[prow * HS + pkb]     = *(const u16x8*)&W[prow * 64 + pkb];
    *(u16x8*)&Wt[prow * HS + pkb + 8] = *(const u16x8*)&W[prow * 64 + pkb + 8];
    __syncthreads();
    f32x4v acc[4];
    #pragma unroll
    for (int c = 0; c < 4; ++c) { acc[c][0] = 0.f; acc[c][1] = 0.f; acc[c][2] = 0.f; acc[c][3] = 0.f; }
    mfma_stage(Xb, Wt, m0, lane, acc, false);
    #pragma unroll
    for (int c4 = 0; c4 < 4; ++c4) {
        #pragma unroll
        for (int r = 0; r < 4; ++r) {
            const int n = nb + m0 + (quad << 2) + r;
            const int col = (c4 << 4) + idx;
            Hb[(size_t)n * 1024 + (l << 6) + col] = f2bf(acc[c4][r]);
        }
    }
}

// ---------------- transpose Hb[n][l][64] -> HbT[n][64][16] ----------------
__global__ __launch_bounds__(256) void k_hbT(const unsigned short* __restrict__ Hb,
    unsigned short* __restrict__ HbT)
{
    const int n = (blockIdx.x << 2) + (threadIdx.x >> 6);
    const int c = threadIdx.x & 63;
    u16x8 a, b;
    #pragma unroll
    for (int l = 0; l < 8; ++l) {
        a[l] = Hb[(size_t)n * 1024 + (l << 6) + c];
        b[l] = Hb[(size_t)n * 1024 + ((l + 8) << 6) + c];
    }
    *(u16x8*)&HbT[(size_t)n * 1024 + c * 16]     = a;
    *(u16x8*)&HbT[(size_t)n * 1024 + c * 16 + 8] = b;
}

// ---------------- lin_out GEMM (MFMA): A fp32 -> H2 bf16 ----------------
__global__ __launch_bounds__(256) void k_lgemm(const float* __restrict__ X,
    const unsigned short* __restrict__ WT, unsigned short* __restrict__ H2b)
{
    __shared__ unsigned short Xb[64 * HS];
    __shared__ unsigned short Wt[64 * HS];
    const int l  = blockIdx.y;
    const int nb = blockIdx.x << 6;
    const int t  = threadIdx.x;
    const int lane = t & 63;
    const int m0   = (t >> 6) << 4;
    const int quad = lane >> 4;
    const int idx  = lane & 15;
    const int prow = t >> 2, pkb = (t & 3) << 4;
    const float* Xp = X + (size_t)l * NC + (size_t)nb * 64;
    #pragma unroll
    for (int k = 0; k < 16; ++k) {
        const int i = t + (k << 8);
        Xb[(i >> 6) * HS + (i & 63)] = f2bf(Xp[i]);
    }
    const unsigned short* W = WT + lmap_rt(l) * 4096;
    *(u16x8*)&Wt[prow * HS + pkb]     = *(const u16x8*)&W[prow * 64 + pkb];
    *(u16x8*)&Wt[prow * HS + pkb + 8] = *(const u16x8*)&W[prow * 64 + pkb + 8];
    __syncthreads();
    f32x4v acc[4];
    #pragma unroll
    for (int c = 0; c < 4; ++c) { acc[c][0] = 0.f; acc[c][1] = 0.f; acc[c][2] = 0.f; acc[c][3] = 0.f; }
    mfma_stage(Xb, Wt, m0, lane, acc, false);
    unsigned short* Op = H2b + (size_t)l * NC + (size_t)nb * 64;
    #pragma unroll
    for (int c4 = 0; c4 < 4; ++c4) {
        #pragma unroll
        for (int r = 0; r < 4; ++r) {
            const int row = m0 + (quad << 2) + r;
            Op[(row << 6) + (c4 << 4) + idx] = f2bf(acc[c4][r]);
        }
    }
}

// ---------------- sc GEMM over element buckets (MFMA): Fb bf16 -> scb bf16 ----------------
__global__ __launch_bounds__(256) void k_sc(const unsigned short* __restrict__ Fb,
    const unsigned short* __restrict__ WscT, const int* __restrict__ perm,
    const int* __restrict__ elem, unsigned short* __restrict__ scb)
{
    __shared__ unsigned short Xb[64 * HS];
    __shared__ unsigned short Wt[64 * HS];
    __shared__ int rows[64];
    const int l  = blockIdx.y;
    const int tb = blockIdx.x << 6;
    const int t  = threadIdx.x;
    if (t < 64) rows[t] = perm[tb + t];
    __syncthreads();
    if (rows[0] < 0) return;
    const int lane = t & 63;
    const int m0   = (t >> 6) << 4;
    const int quad = lane >> 4;
    const int idx  = lane & 15;
    const int prow = t >> 2, pkb = (t & 3) << 4;
    const unsigned short* W = WscT + elem[rows[0]] * 4096;
    *(u16x8*)&Wt[prow * HS + pkb]     = *(const u16x8*)&W[prow * 64 + pkb];
    *(u16x8*)&Wt[prow * HS + pkb + 8] = *(const u16x8*)&W[prow * 64 + pkb + 8];
    {
        const int n = rows[prow];
        u16x8 z;
        #pragma unroll
        for (int j = 0; j < 8; ++j) z[j] = 0;
        u16x8 x0 = z, x1 = z;
        if (n >= 0) {
            const unsigned short* src = Fb + (size_t)l * NC + (size_t)n * 64 + pkb;
            x0 = *(const u16x8*)&src[0];
            x1 = *(const u16x8*)&src[8];
        }
        *(u16x8*)&Xb[prow * HS + pkb]     = x0;
        *(u16x8*)&Xb[prow * HS + pkb + 8] = x1;
    }
    __syncthreads();
    f32x4v acc[4];
    #pragma unroll
    for (int c = 0; c < 4; ++c) { acc[c][0] = 0.f; acc[c][1] = 0.f; acc[c][2] = 0.f; acc[c][3] = 0.f; }
    mfma_stage(Xb, Wt, m0, lane, acc, false);
    #pragma unroll
    for (int c4 = 0; c4 < 4; ++c4) {
        #pragma unroll
        for (int r = 0; r < 4; ++r) {
            const int n = rows[m0 + (quad << 2) + r];
            if (n >= 0) scb[(size_t)l * NC + (size_t)n * 64 + (c4 << 4) + idx] = f2bf(acc[c4][r]);
        }
    }
}

// ---------------- fused edge MLP + aggregation (Y in registers, readlane broadcast) ----------------
__global__ __launch_bounds__(256) void k_edge(const float4* __restrict__ geomv,
    const int* __restrict__ spck, const unsigned short* __restrict__ WT,
    const unsigned short* __restrict__ HbT, const int* __restrict__ roff,
    float* __restrict__ A)
{
    __shared__ unsigned short hbf[64 * HS];
    __shared__ unsigned short wtb[64 * HS];
    __shared__ unsigned short wfull[64 * WS2];
    __shared__ int   sps[64];
    __shared__ int   rinfo[2];
    const int t = threadIdx.x;
    const int lane = t & 63;
    const int wid  = t >> 6;
    const int m0   = wid << 4;
    const int quad = lane >> 4;
    const int idx  = lane & 15;
    const int prow = t >> 2, pkb = (t & 3) << 4;
    const int w0 = blockIdx.x << 6;
    const int w1 = w0 + 64;
    if (t == 0) {
        int lo = 0, hi = N - 1;
        while (lo < hi) { const int mid = (lo + hi + 1) >> 1; if (roff[mid] <= w0) lo = mid; else hi = mid - 1; }
        rinfo[0] = lo;
    } else if (t == 1) {
        const int w1m = w0 + 63;
        int lo = 0, hi = N - 1;
        while (lo < hi) { const int mid = (lo + hi + 1) >> 1; if (roff[mid] <= w1m) lo = mid; else hi = mid - 1; }
        rinfo[1] = lo;
    }
    // per-lane Y for edge w0+lane (all waves; zeroed beyond RMAX)
    float yreg[16];
    {
        const float4 g = geomv[w0 + lane];
        const float x = g.x, y = g.y, z = g.z;
        const float xx = x * x, yy = y * y, zz = z * z;
        yreg[0] = 1.f;
        yreg[1] = 1.7320508f * x;  yreg[2] = 1.7320508f * y;  yreg[3] = 1.7320508f * z;
        yreg[4] = 3.8729833f * x * y;  yreg[5] = 3.8729833f * y * z;
        yreg[6] = 0.5f * 2.2360680f * (3.f * zz - 1.f);
        yreg[7] = 3.8729833f * x * z;  yreg[8] = 0.5f * 3.8729833f * (xx - yy);
        yreg[9]  = 2.0916500f * y * (3.f * xx - yy);
        yreg[10] = 10.2469508f * x * y * z;
        yreg[11] = 1.6201852f * y * (5.f * zz - 1.f);
        yreg[12] = 0.5f * 2.6457513f * z * (5.f * zz - 3.f);
        yreg[13] = 1.6201852f * x * (5.f * zz - 1.f);
        yreg[14] = 0.5f * 10.2469508f * z * (xx - yy);
        yreg[15] = 2.0916500f * x * (xx - 3.f * yy);
        const float m = (g.w < RMAX) ? 1.f : 0.f;
        #pragma unroll
        for (int l = 0; l < 16; ++l) yreg[l] *= m;
        if (t < 64) {
            sps[t] = spck[w0 + t];
            const float r = g.w;
            const float u  = r * 0.2f;
            const float u2 = u * u, u5 = u2 * u2 * u;
            const float fc = 1.f - 21.f * u5 + 35.f * u5 * u - 15.f * u5 * u2;
            float pref = 0.63245553f * fc / (r + 1e-9f);
            if (u >= 1.f) pref = 0.f;
            const float piu = 3.14159265358979f * u;
            #pragma unroll
            for (int b = 0; b < 8; ++b) hbf[t * HS + b] = f2bf(__sinf((float)(b + 1) * piu) * pref);
        }
    }
    {
        const int n = t >> 2, k = (t & 3) << 1;
        wtb[n * HS + k]     = WT[n * 8 + k];
        wtb[n * HS + k + 1] = WT[n * 8 + k + 1];
    }
    u16x8 pf0 = *(const u16x8*)&WT[512 + prow * 64 + pkb];
    u16x8 pf1 = *(const u16x8*)&WT[512 + prow * 64 + pkb + 8];
    __syncthreads();
    f32x4v acc[4];
    #pragma unroll
    for (int c = 0; c < 4; ++c) { acc[c][0] = 0.f; acc[c][1] = 0.f; acc[c][2] = 0.f; acc[c][3] = 0.f; }
    mfma_stage(hbf, wtb, m0, lane, acc, true);
    __syncthreads();
    #pragma unroll
    for (int c4 = 0; c4 < 4; ++c4)
        #pragma unroll
        for (int r = 0; r < 4; ++r)
            hbf[(m0 + (quad << 2) + r) * HS + (c4 << 4) + idx] = f2bf(silu(acc[c4][r]));
    *(u16x8*)&wtb[prow * HS + pkb]     = pf0;
    *(u16x8*)&wtb[prow * HS + pkb + 8] = pf1;
    pf0 = *(const u16x8*)&WT[4608 + prow * 64 + pkb];
    pf1 = *(const u16x8*)&WT[4608 + prow * 64 + pkb + 8];
    __syncthreads();
    #pragma unroll
    for (int c = 0; c < 4; ++c) { acc[c][0] = 0.f; acc[c][1] = 0.f; acc[c][2] = 0.f; acc[c][3] = 0.f; }
    mfma_stage(hbf, wtb, m0, lane, acc, false);
    __syncthreads();
    #pragma unroll
    for (int c4 = 0; c4 < 4; ++c4)
        #pragma unroll
        for (int r = 0; r < 4; ++r)
            hbf[(m0 + (quad << 2) + r) * HS + (c4 << 4) + idx] = f2bf(silu(acc[c4][r]));
    *(u16x8*)&wtb[prow * HS + pkb]     = pf0;
    *(u16x8*)&wtb[prow * HS + pkb + 8] = pf1;
    pf0 = *(const u16x8*)&WT[8704 + prow * 64 + pkb];
    pf1 = *(const u16x8*)&WT[8704 + prow * 64 + pkb + 8];
    __syncthreads();
    #pragma unroll
    for (int c = 0; c < 4; ++c) { acc[c][0] = 0.f; acc[c][1] = 0.f; acc[c][2] = 0.f; acc[c][3] = 0.f; }
    mfma_stage(hbf, wtb, m0, lane, acc, false);
    __syncthreads();
    #pragma unroll
    for (int c4 = 0; c4 < 4; ++c4)
        #pragma unroll
        for (int r = 0; r < 4; ++r)
            hbf[(m0 + (quad << 2) + r) * HS + (c4 << 4) + idx] = f2bf(silu(acc[c4][r]));
    *(u16x8*)&wtb[prow * HS + pkb]     = pf0;
    *(u16x8*)&wtb[prow * HS + pkb + 8] = pf1;
    pf0 = *(const u16x8*)&WT[8704 + 4096 + prow * 64 + pkb];
    pf1 = *(const u16x8*)&WT[8704 + 4096 + prow * 64 + pkb + 8];
    __syncthreads();
    for (int cc = 0; cc < 4; ++cc) {
        #pragma unroll
        for (int c = 0; c < 4; ++c) { acc[c][0] = 0.f; acc[c][1] = 0.f; acc[c][2] = 0.f; acc[c][3] = 0.f; }
        mfma_stage(hbf, wtb, m0, lane, acc, false);
        __syncthreads();
        #pragma unroll
        for (int c4 = 0; c4 < 4; ++c4)
            #pragma unroll
            for (int r = 0; r < 4; ++r)
                wfull[(m0 + (quad << 2) + r) * WS2 + (cc << 6) + (c4 << 4) + idx] = f2bf(acc[c4][r]);
        if (cc < 3) {
            *(u16x8*)&wtb[prow * HS + pkb]     = pf0;
            *(u16x8*)&wtb[prow * HS + pkb + 8] = pf1;
            if (cc < 2) {
                pf0 = *(const u16x8*)&WT[8704 + (cc + 2) * 4096 + prow * 64 + pkb];
                pf1 = *(const u16x8*)&WT[8704 + (cc + 2) * 4096 + prow * 64 + pkb + 8];
            }
        }
        __syncthreads();
    }
    const int r0 = rinfo[0], r1 = rinfo[1];
    constexpr int LM[16] = {0,1,1,1,2,2,2,2,2,3,3,3,3,3,3,3};
    for (int r = r0 + wid; r <= r1; r += 4) {
        const int ra = roff[r], rb = roff[r + 1];
        const int ja = ra > w0 ? ra : w0;
        const int jb = rb < w1 ? rb : w1;
        float a16[16];
        #pragma unroll
        for (int l = 0; l < 16; ++l) a16[l] = 0.f;
        if (ja < jb) {
            u16x8 hA0, hB0, hA1, hB1;
            {
                const int s = sps[ja - w0];
                hA0 = *(const u16x8*)&HbT[(size_t)s * 1024 + lane * 16];
                hB0 = *(const u16x8*)&HbT[(size_t)s * 1024 + lane * 16 + 8];
            }
            hA1 = hA0; hB1 = hB0;
            if (ja + 1 < jb) {
                const int s = sps[ja + 1 - w0];
                hA1 = *(const u16x8*)&HbT[(size_t)s * 1024 + lane * 16];
                hB1 = *(const u16x8*)&HbT[(size_t)s * 1024 + lane * 16 + 8];
            }
            for (int j = ja; j < jb; ++j) {
                const int jj = j - w0;
                float hc[16];
                #pragma unroll
                for (int l = 0; l < 8; ++l) { hc[l] = bf2f(hA0[l]); hc[l + 8] = bf2f(hB0[l]); }
                hA0 = hA1; hB0 = hB1;
                if (j + 2 < jb) {
                    const int s = sps[jj + 2];
                    hA1 = *(const u16x8*)&HbT[(size_t)s * 1024 + lane * 16];
                    hB1 = *(const u16x8*)&HbT[(size_t)s * 1024 + lane * 16 + 8];
                }
                // broadcast edge jj's Y from lane jj (jj is wave-uniform)
                float sY[16];
                #pragma unroll
                for (int l = 0; l < 16; ++l) sY[l] = rdlane(yreg[l], jj);
                float se = 0.f;
                #pragma unroll
                for (int l = 0; l < 16; ++l) se += hc[l] * sY[l];
                se *= 0.0625f;
                const ushort4 wq = *(const ushort4*)&wfull[jj * WS2 + (lane << 2)];
                const float wl[4] = { bf2f(wq.x) * se, bf2f(wq.y) * se, bf2f(wq.z) * se, bf2f(wq.w) * se };
                #pragma unroll
                for (int l = 0; l < 16; ++l) a16[l] += wl[LM[l]] * sY[l];
            }
        }
        float* Ap = A + (size_t)r * 64 + lane;
        if (ra >= w0 && rb <= w1) {
            #pragma unroll
            for (int l = 0; l < 16; ++l) Ap[(size_t)l * NC] = a16[l];
        } else {
            #pragma unroll
            for (int l = 0; l < 16; ++l) atomicAdd(&Ap[(size_t)l * NC], a16[l]);
        }
    }
}

// ---------------- fused s1 + out: per node tile, loop l; s1 kept in registers ----------------
__global__ __launch_bounds__(256) void k_out2(const unsigned short* __restrict__ H2b,
    const unsigned short* __restrict__ WpT, const unsigned short* __restrict__ scb,
    unsigned short* __restrict__ Fb)
{
    __shared__ unsigned short Xb[64 * HS];
    __shared__ unsigned short Wt3[3][64 * HS];
    const int nb = blockIdx.x << 6;
    const int lq = blockIdx.y;          // l quarter: handles l in [lq*4, lq*4+4)
    const int t  = threadIdx.x;
    const int lane = t & 63;
    const int m0   = (t >> 6) << 4;
    const int quad = lane >> 4;
    const int idx  = lane & 15;
    const int prow = t >> 2, pkb = (t & 3) << 4;
    #pragma unroll
    for (int p = 0; p < 3; ++p) {
        *(u16x8*)&Wt3[p][prow * HS + pkb]     = *(const u16x8*)&WpT[p * 4096 + prow * 64 + pkb];
        *(u16x8*)&Wt3[p][prow * HS + pkb + 8] = *(const u16x8*)&WpT[p * 4096 + prow * 64 + pkb + 8];
    }
    // pass 1: s1 for this thread's slots (rows prow, cols pkb..pkb+15), over all 16 l
    float sv[16];
    #pragma unroll
    for (int k = 0; k < 16; ++k) sv[k] = 0.f;
    for (int l = 0; l < 16; ++l) {
        const unsigned short* Xp = H2b + (size_t)l * NC + (size_t)nb * 64;
        const u16x8 x0 = *(const u16x8*)&Xp[prow * 64 + pkb];
        const u16x8 x1 = *(const u16x8*)&Xp[prow * 64 + pkb + 8];
        #pragma unroll
        for (int j = 0; j < 8; ++j) {
            const float a = bf2f(x0[j]); sv[j] += a * a;
            const float b = bf2f(x1[j]); sv[8 + j] += b * b;
        }
    }
    __syncthreads();
    // pass 2: 4 l-values
    for (int li = 0; li < 4; ++li) {
        const int l = (lq << 2) + li;
        const unsigned short* Xp = H2b + (size_t)l * NC + (size_t)nb * 64;
        float av[16];
        {
            const u16x8 x0 = *(const u16x8*)&Xp[prow * 64 + pkb];
            const u16x8 x1 = *(const u16x8*)&Xp[prow * 64 + pkb + 8];
            #pragma unroll
            for (int j = 0; j < 8; ++j) { av[j] = bf2f(x0[j]); av[8 + j] = bf2f(x1[j]); }
        }
        f32x4v acc[4];
        #pragma unroll
        for (int c = 0; c < 4; ++c) { acc[c][0] = 0.f; acc[c][1] = 0.f; acc[c][2] = 0.f; acc[c][3] = 0.f; }
        for (int p = 0; p < 3; ++p) {
            u16x8 x0, x1;
            #pragma unroll
            for (int j = 0; j < 8; ++j) { x0[j] = f2bf(av[j]); x1[j] = f2bf(av[8 + j]); }
            *(u16x8*)&Xb[prow * HS + pkb]     = x0;
            *(u16x8*)&Xb[prow * HS + pkb + 8] = x1;
            #pragma unroll
            for (int k = 0; k < 16; ++k) av[k] *= sv[k];
            __syncthreads();
            mfma_stage(Xb, Wt3[p], m0, lane, acc, false);
            __syncthreads();
        }
        #pragma unroll
        for (int c4 = 0; c4 < 4; ++c4) {
            #pragma unroll
            for (int r = 0; r < 4; ++r) {
                const int row = m0 + (quad << 2) + r;
                const int col = (c4 << 4) + idx;
                const size_t id = (size_t)l * NC + (size_t)(nb + row) * 64 + col;
                Fb[id] = f2bf(acc[c4][r] + bf2f(scb[id]));
            }
        }
    }
}

// ---------------- readout (bf16 F) ----------------
__global__ __launch_bounds__(256) void k_read(const unsigned short* __restrict__ Fb,
    const float* __restrict__ q, const int* __restrict__ batch,
    const float* __restrict__ Wr0, const float* __restrict__ Wa,
    const float* __restrict__ Wb, const float* __restrict__ Wq,
    float* __restrict__ acc, int last)
{
    __shared__ float sred[G];
    if (threadIdx.x < G) sred[threadIdx.x] = 0.f;
    __syncthreads();
    const int n = blockIdx.x * 256 + threadIdx.x;
    if (n < N) {
        float a16[16];
        #pragma unroll
        for (int j = 0; j < 16; ++j) a16[j] = 0.f;
        float ar = 0.f, aq = 0.f;
        const unsigned short* f = Fb + (size_t)n * 64;
        for (int c = 0; c < 64; ++c) {
            const float fv = bf2f(f[c]);
            aq += fv * Wq[c];
            if (last) {
                #pragma unroll
                for (int j = 0; j < 16; ++j) a16[j] += fv * Wa[c * 16 + j];
            } else ar += fv * Wr0[c];
        }
        float en;
        if (last) {
            en = 0.f;
            #pragma unroll
            for (int j = 0; j < 16; ++j) en += silu(a16[j]) * Wb[j];
        } else en = ar;
        en += q[n] * aq;
        atomicAdd(&sred[batch[n]], en);
    }
    __syncthreads();
    if (threadIdx.x < G) atomicAdd(&acc[threadIdx.x * 5], sred[threadIdx.x]);
}

// ---------------- Ewald ----------------
__global__ __launch_bounds__(256) void k_kvec(const float* __restrict__ rcell,
    float* __restrict__ kvec, float* __restrict__ k2)
{
    const int idx = blockIdx.x * 256 + threadIdx.x;
    if (idx >= G * NK) return;
    const int g = idx / NK, k = idx % NK;
    const int kk = k + (k >= 171 ? 1 : 0);
    const int a = kk / 49 - 3, b = (kk / 7) % 7 - 3, c = kk % 7 - 3;
    const float* rc = rcell + g * 9;
    float s = 0.f;
    #pragma unroll
    for (int i = 0; i < 3; ++i) {
        const float kv = 6.283185307f * ((float)a * rc[0 + i] + (float)b * rc[3 + i] + (float)c * rc[6 + i]);
        kvec[idx * 3 + i] = kv;
        s += kv * kv;
    }
    k2[idx] = s;
}

__global__ __launch_bounds__(256) void k_phase(const float* __restrict__ pos,
    const float* __restrict__ q, const float* __restrict__ kvec,
    float* __restrict__ Sr, float* __restrict__ Si)
{
    __shared__ float kvs[38 * 3];
    __shared__ float srs[38], sis[38];
    const int g = blockIdx.z, kc = blockIdx.x, ncb = blockIdx.y;
    const int kbase = kc * 38;
    if (threadIdx.x < 38 * 3) kvs[threadIdx.x] = kvec[((size_t)g * NK + kbase) * 3 + threadIdx.x];
    if (threadIdx.x < 38) { srs[threadIdx.x] = 0.f; sis[threadIdx.x] = 0.f; }
    __syncthreads();
    const int t = threadIdx.x;
    float px = 0.f, py = 0.f, pz = 0.f, qn = 0.f;
    if (t < 250) {
        const int n = g * NGR + ncb * 250 + t;
        px = pos[n * 3]; py = pos[n * 3 + 1]; pz = pos[n * 3 + 2]; qn = q[n];
    }
    const int lane = t & 63;
    for (int j = 0; j < 38; ++j) {
        const float ph = px * kvs[j * 3] + py * kvs[j * 3 + 1] + pz * kvs[j * 3 + 2];
        float sv, cv;
        __sincosf(ph, &sv, &cv);
        float vr = qn * cv, vi = qn * sv;
        #pragma unroll
        for (int o = 32; o > 0; o >>= 1) { vr += __shfl_down(vr, o, 64); vi += __shfl_down(vi, o, 64); }
        if (lane == 0) { atomicAdd(&srs[j], vr); atomicAdd(&sis[j], vi); }
    }
    __syncthreads();
    if (t < 38) {
        atomicAdd(&Sr[g * NK + kbase + t], srs[t]);
        atomicAdd(&Si[g * NK + kbase + t], sis[t]);
    }
}

__global__ __launch_bounds__(512) void k_final(const float* __restrict__ k2,
    const float* __restrict__ Sr, const float* __restrict__ Si,
    const float* __restrict__ vol, const float* __restrict__ acc,
    float* __restrict__ out)
{
    __shared__ float red[512];
    const int g = blockIdx.x, t = threadIdx.x;
    float v = 0.f;
    if (t < NK) {
        const float kk = k2[g * NK + t];
        const float sr = Sr[g * NK + t], si = Si[g * NK + t];
        v = __expf(-0.5f * kk) * (sr * sr + si * si) / kk;
    }
    red[t] = v;
    __syncthreads();
    for (int s2 = 256; s2 > 0; s2 >>= 1) {
        if (t < s2) red[t] += red[t + s2];
        __syncthreads();
    }
    if (t == 0) {
        const float Ees = 6.283185307f / vol[g] * red[0];
        out[g]     = acc[g * 5 + 0] + Ees;
        out[4 + g] = acc[g * 5 + 1];
        out[8 + g * 3 + 0] = acc[g * 5 + 2];
        out[8 + g * 3 + 1] = acc[g * 5 + 3];
        out[8 + g * 3 + 2] = acc[g * 5 + 4];
    }
}

extern "C" void kernel_launch(void* const* d_in, const int* in_sizes, int n_in,
                              void* d_out, int out_size, void* d_ws, size_t ws_size,
                              hipStream_t stream)
{
    const float* na    = (const float*)d_in[0];
    const float* pos   = (const float*)d_in[1];
    const float* shif  = (const float*)d_in[2];
    const float* q     = (const float*)d_in[3];
    const float* rcell = (const float*)d_in[5];
    const float* vol   = (const float*)d_in[6];
    const int*   ei    = (const int*)d_in[7];
    const int*   batch = (const int*)d_in[8];
    const float* embW  = (const float*)d_in[9];
    const float* qcoef = (const float*)d_in[10];
    const float* rW1   = (const float*)d_in[11];
    const float* rW2   = (const float*)d_in[12];
    const float* rW3   = (const float*)d_in[13];
    const float* rW4   = (const float*)d_in[14];
    const float* lup   = (const float*)d_in[15];
    const float* lout  = (const float*)d_in[16];
    const float* Wsc   = (const float*)d_in[17];
    const float* Wp    = (const float*)d_in[18];
    const float* Wr0   = (const float*)d_in[19];
    const float* Wa    = (const float*)d_in[20];
    const float* Wb    = (const float*)d_in[21];
    const float* Wq    = (const float*)d_in[22];
    const float* aE    = (const float*)d_in[23];
    float* out = (float*)d_out;

    float* wsf  = (float*)d_ws;
    unsigned short* Fb = (unsigned short*)wsf;           // bf16 [16][N][64]
    float* A    = wsf + 8192000;        // [16][N][64] fp32 (agg out); later aliased as scb bf16
    unsigned short* scb = (unsigned short*)A;            // bf16 [16][N][64]
    float* R    = A + 8192000;
    unsigned short* H2b   = (unsigned short*)R;              // bf16 [16][N][64]
    unsigned short* HbT   = (unsigned short*)R;              // bf16 [N][64][16]
    unsigned short* Hbtmp = (unsigned short*)(R + 4096000);  // bf16 [N][16][64] (transient)
    float* s1   = R + 20480000;         // (unused; kept for layout)
    float* kvec = s1 + 512000;          // [G*342][3]
    float* k2   = kvec + 4104;
    float* Sr   = k2 + 1368;
    float* Si   = Sr + 1368;
    float* acc  = Si + 1368;            // [G][5]
    int*   elem = (int*)(acc + 32);     // [N]
    int*   perm = elem + 8000;          // [8640]
    int*   counts = perm + 8640;        // [16]
    int*   cursor = counts + 16;        // [16]
    int*   offs   = cursor + 16;        // [16]
    int*   roff   = offs + 16;          // [N+1]
    int*   cnt    = roff + 8001;        // [N]
    int*   cur    = cnt + 8000;         // [N]
    int*   elist  = cur + 8000;         // [E]
    unsigned short* WTb = (unsigned short*)(((uintptr_t)(elist + E) + 31) & ~(uintptr_t)31); // [2*WT_T]
    unsigned short* WpT = WTb + 2 * WT_T;                // [24576]
    float4* geomv = (float4*)(WpT + 24576);              // [E]
    int*    spck  = (int*)(geomv + E);                   // [E]
    unsigned short* WlupT  = (unsigned short*)(spck + E); // [32768]
    unsigned short* WloutT = WlupT + 32768;               // [32768]
    unsigned short* WscT   = WloutT + 32768;              // [81920]

    hipMemsetAsync(Fb, 0, 8192000 * sizeof(unsigned short), stream);
    hipMemsetAsync(Sr, 0, (1368 * 2 + 32) * sizeof(float), stream);
    hipMemsetAsync(perm, 0xFF, 8640 * sizeof(int), stream);
    hipMemsetAsync(counts, 0, 32 * sizeof(int), stream);
    hipMemsetAsync(cnt, 0, 16000 * sizeof(int), stream);

    k_init<<<32, 256, 0, stream>>>(na, q, pos, batch, aE, elem, counts, acc);
    k_feat0<<<2000, 256, 0, stream>>>(elem, embW, Fb);
    k_offs<<<1, 64, 0, stream>>>(counts, offs);
    k_scatter<<<32, 256, 0, stream>>>(elem, offs, cursor, perm);
    k_gcnt<<<500, 256, 0, stream>>>(ei, cnt);
    k_goff<<<1, 1024, 0, stream>>>(cnt, roff);
    k_gscat<<<500, 256, 0, stream>>>(ei, roff, cur, elist);
    k_geom<<<500, 256, 0, stream>>>(pos, shif, ei, elist, geomv, spck);
    k_wprep_all<<<868, 256, 0, stream>>>(rW1, rW2, rW3, rW4, Wp, lup, lout, Wsc,
                                         WTb, WpT, WlupT, WloutT, WscT);
    k_kvec<<<6, 256, 0, stream>>>(rcell, kvec, k2);
    k_phase<<<dim3(9, 8, G), 256, 0, stream>>>(pos, q, kvec, Sr, Si);

    for (int t = 0; t < 2; ++t) {
        k_lgemm_hb<<<dim3(125, 16), 256, 0, stream>>>(Fb, q, qcoef + t * 64, WlupT + t * 16384, Hbtmp);
        k_hbT<<<2000, 256, 0, stream>>>(Hbtmp, HbT);
        hipMemsetAsync(A, 0, 8192000 * sizeof(float), stream);
        k_edge<<<2000, 256, 0, stream>>>(geomv, spck, WTb + t * WT_T, HbT, roff, A);
        k_lgemm<<<dim3(125, 16), 256, 0, stream>>>(A, WloutT + t * 16384, H2b);
        k_sc<<<dim3(135, 16), 256, 0, stream>>>(Fb, WscT + t * 40960, perm, elem, scb);
        k_out2<<<dim3(125, 4), 256, 0, stream>>>(H2b, WpT + t * 12288, scb, Fb);
        k_read<<<32, 256, 0, stream>>>(Fb, q, batch, Wr0, Wa, Wb, Wq + t * 64, acc, t == 1);
    }
    k_final<<<G, 512, 0, stream>>>(k2, Sr, Si, vol, acc, out);
}

// Round 13
// 536.440 us; speedup vs baseline: 1.0290x; 1.0290x over previous
//
#include <hip/hip_runtime.h>
#include <hip/hip_bf16.h>

constexpr int N    = 8000;
constexpr int E    = 128000;
constexpr int G    = 4;
constexpr int NEL  = 10;
constexpr int NGR  = N / G;          // 2000
constexpr int NC   = N * 64;         // 512000
constexpr int NK   = 342;            // Ewald vectors
constexpr float RMAX = 5.0f;
constexpr int HS = 72;               // padded LDS row stride (bf16) for MFMA tiles
constexpr int WS2 = 260;             // wfull row stride (ushorts)
constexpr int WT_T = 25088;          // per-t size of transposed radial-weight block (ushorts)

typedef __bf16 bf16x8 __attribute__((ext_vector_type(8)));
typedef float  f32x4v __attribute__((ext_vector_type(4)));
typedef unsigned short u16x8 __attribute__((ext_vector_type(8)));

__device__ __forceinline__ int lmap_rt(int l) { return (l >= 1) + (l >= 4) + (l >= 9); }
__device__ __forceinline__ float silu(float x) { return x / (1.f + __expf(-x)); }
__device__ __forceinline__ float bf2f(unsigned short u) { return __uint_as_float(((unsigned)u) << 16); }
__device__ __forceinline__ unsigned short f2bf(float f) {
    __hip_bfloat16 h = __float2bfloat16(f);
    return *(unsigned short*)&h;
}
__device__ __forceinline__ float rdlane(float v, int lane) {
    return __uint_as_float(__builtin_amdgcn_readlane(__float_as_uint(v), lane));
}

// MFMA 64x64(xK) stage: hsrc rows = M (stride HS), wt rows = N (stride HS), K=64 (or 8)
__device__ __forceinline__ void mfma_stage(const unsigned short* hsrc, const unsigned short* wt,
                                           int m0, int lane, f32x4v acc[4], bool k8only)
{
    const int quad = lane >> 4;
    const int idx  = lane & 15;
    bf16x8 bz;
    #pragma unroll
    for (int i = 0; i < 8; ++i) bz[i] = (__bf16)0.f;
    bf16x8 a0 = bz, a1 = bz;
    const int mrow = m0 + idx;
    if (k8only) {
        if (quad == 0) a0 = *(const bf16x8*)&hsrc[mrow * HS];
    } else {
        a0 = *(const bf16x8*)&hsrc[mrow * HS + (quad << 3)];
        a1 = *(const bf16x8*)&hsrc[mrow * HS + 32 + (quad << 3)];
    }
    #pragma unroll
    for (int c4 = 0; c4 < 4; ++c4) {
        const int nrow = (c4 << 4) + idx;
        if (k8only) {
            bf16x8 b0 = bz;
            if (quad == 0) b0 = *(const bf16x8*)&wt[nrow * HS];
            acc[c4] = __builtin_amdgcn_mfma_f32_16x16x32_bf16(a0, b0, acc[c4], 0, 0, 0);
        } else {
            const bf16x8 b0 = *(const bf16x8*)&wt[nrow * HS + (quad << 3)];
            const bf16x8 b1 = *(const bf16x8*)&wt[nrow * HS + 32 + (quad << 3)];
            acc[c4] = __builtin_amdgcn_mfma_f32_16x16x32_bf16(a0, b0, acc[c4], 0, 0, 0);
            acc[c4] = __builtin_amdgcn_mfma_f32_16x16x32_bf16(a1, b1, acc[c4], 0, 0, 0);
        }
    }
}

// ---------------- init: elem, hist, e0/charge/dipole ----------------
__global__ __launch_bounds__(256) void k_init(const float* __restrict__ na,
    const float* __restrict__ q, const float* __restrict__ pos,
    const int* __restrict__ batch, const float* __restrict__ aE,
    int* __restrict__ elem, int* __restrict__ counts, float* __restrict__ acc)
{
    __shared__ float s[G * 5];
    if (threadIdx.x < G * 5) s[threadIdx.x] = 0.f;
    __syncthreads();
    const int n = blockIdx.x * 256 + threadIdx.x;
    if (n < N) {
        int el = 0; float best = na[n * NEL];
        #pragma unroll
        for (int j = 1; j < NEL; ++j) { float v = na[n * NEL + j]; if (v > best) { best = v; el = j; } }
        elem[n] = el;
        atomicAdd(&counts[el], 1);
        const int g = batch[n];
        const float qn = q[n];
        atomicAdd(&s[g * 5 + 0], aE[el]);
        atomicAdd(&s[g * 5 + 1], qn);
        atomicAdd(&s[g * 5 + 2], qn * pos[n * 3 + 0]);
        atomicAdd(&s[g * 5 + 3], qn * pos[n * 3 + 1]);
        atomicAdd(&s[g * 5 + 4], qn * pos[n * 3 + 2]);
    }
    __syncthreads();
    if (threadIdx.x < G * 5) atomicAdd(&acc[threadIdx.x], s[threadIdx.x]);
}

__global__ __launch_bounds__(256) void k_feat0(const int* __restrict__ elem,
    const float* __restrict__ embW, unsigned short* __restrict__ Fb)
{
    const int i = blockIdx.x * 256 + threadIdx.x;
    if (i < NC) Fb[i] = f2bf(embW[elem[i >> 6] * 64 + (i & 63)]);
}

// ---------------- element bucketing ----------------
__global__ void k_offs(const int* __restrict__ counts, int* __restrict__ offs)
{
    if (threadIdx.x == 0 && blockIdx.x == 0) {
        int o = 0;
        for (int j = 0; j < NEL; ++j) { offs[j] = o; o += (counts[j] + 63) & ~63; }
        offs[NEL] = o;
    }
}
__global__ __launch_bounds__(256) void k_scatter(const int* __restrict__ elem,
    const int* __restrict__ offs, int* __restrict__ cursor, int* __restrict__ perm)
{
    const int n = blockIdx.x * 256 + threadIdx.x;
    if (n < N) {
        const int el = elem[n];
        const int p = atomicAdd(&cursor[el], 1);
        perm[offs[el] + p] = n;
    }
}

// ---------------- receiver CSR build ----------------
__global__ __launch_bounds__(256) void k_gcnt(const int* __restrict__ ei, int* __restrict__ cnt)
{
    const int e = blockIdx.x * 256 + threadIdx.x;
    if (e < E) atomicAdd(&cnt[ei[E + e]], 1);
}
__global__ __launch_bounds__(1024) void k_goff(const int* __restrict__ cnt, int* __restrict__ roff)
{
    __shared__ int part[1024];
    const int t = threadIdx.x;
    const int base = t * 8;
    int loc[8];
    int s = 0;
    #pragma unroll
    for (int i = 0; i < 8; ++i) { loc[i] = s; s += (base + i < N) ? cnt[base + i] : 0; }
    part[t] = s;
    __syncthreads();
    for (int d = 1; d < 1024; d <<= 1) {
        const int v = (t >= d) ? part[t - d] : 0;
        __syncthreads();
        part[t] += v;
        __syncthreads();
    }
    const int excl = (t == 0) ? 0 : part[t - 1];
    #pragma unroll
    for (int i = 0; i < 8; ++i) if (base + i < N) roff[base + i] = excl + loc[i];
    if (t == 0) roff[N] = E;
}
__global__ __launch_bounds__(256) void k_gscat(const int* __restrict__ ei,
    const int* __restrict__ roff, int* __restrict__ cur, int* __restrict__ elist)
{
    const int e = blockIdx.x * 256 + threadIdx.x;
    if (e < E) {
        const int rv = ei[E + e];
        const int p = atomicAdd(&cur[rv], 1);
        elist[roff[rv] + p] = e;
    }
}

// ---------------- per-elist-position geometry precompute ----------------
__global__ __launch_bounds__(256) void k_geom(const float* __restrict__ pos,
    const float* __restrict__ shifts, const int* __restrict__ ei,
    const int* __restrict__ elist, float4* __restrict__ geomv, int* __restrict__ spck)
{
    const int j = blockIdx.x * 256 + threadIdx.x;
    if (j >= E) return;
    const int e = elist[j];
    const int s = ei[e], rv = ei[E + e];
    const float dx = pos[rv * 3 + 0] - pos[s * 3 + 0] + shifts[e * 3 + 0];
    const float dy = pos[rv * 3 + 1] - pos[s * 3 + 1] + shifts[e * 3 + 1];
    const float dz = pos[rv * 3 + 2] - pos[s * 3 + 2] + shifts[e * 3 + 2];
    const float r = sqrtf(dx * dx + dy * dy + dz * dz);
    const float inv = 1.f / (r + 1e-9f);
    float4 g;
    g.x = dx * inv; g.y = dy * inv; g.z = dz * inv; g.w = r;
    geomv[j] = g;
    spck[j] = s;
}

// ---------------- merged weight transpose+bf16 prep (runs once) ----------------
__global__ __launch_bounds__(256) void k_wprep_all(const float* __restrict__ rW1,
    const float* __restrict__ rW2, const float* __restrict__ rW3,
    const float* __restrict__ rW4, const float* __restrict__ Wp,
    const float* __restrict__ lup, const float* __restrict__ lout,
    const float* __restrict__ Wsc,
    unsigned short* __restrict__ WT, unsigned short* __restrict__ WpT,
    unsigned short* __restrict__ WlupT, unsigned short* __restrict__ WloutT,
    unsigned short* __restrict__ WscT)
{
    const int gidx = blockIdx.x * 256 + threadIdx.x;
    if (gidx < 2 * WT_T) {
        const int t = gidx / WT_T;
        const int r = gidx % WT_T;
        float v;
        if (r < 512) {
            const int n = r >> 3, k = r & 7;
            v = rW1[t * 512 + k * 64 + n];
        } else if (r < 4608) {
            const int i = r - 512, n = i >> 6, k = i & 63;
            v = rW2[t * 4096 + k * 64 + n];
        } else if (r < 8704) {
            const int i = r - 4608, n = i >> 6, k = i & 63;
            v = rW3[t * 4096 + k * 64 + n];
        } else {
            const int i = r - 8704, n = i >> 6, k = i & 63;
            v = rW4[t * 16384 + k * 256 + n];
        }
        WT[gidx] = f2bf(v);
    } else if (gidx < 2 * WT_T + 24576) {
        const int idx = gidx - 2 * WT_T;
        const int i  = idx & 4095;
        const int d = i >> 6, c = i & 63;
        WpT[idx] = f2bf(Wp[(size_t)(idx >> 12) * 4096 + c * 64 + d]);
    } else if (gidx < 2 * WT_T + 24576 + 32768) {
        const int idx = gidx - (2 * WT_T + 24576);
        const int i = idx & 4095, d = i >> 6, c = i & 63;
        WlupT[idx] = f2bf(lup[(idx >> 12) * 4096 + c * 64 + d]);
    } else if (gidx < 2 * WT_T + 24576 + 65536) {
        const int idx = gidx - (2 * WT_T + 24576 + 32768);
        const int i = idx & 4095, d = i >> 6, c = i & 63;
        WloutT[idx] = f2bf(lout[(idx >> 12) * 4096 + c * 64 + d]);
    } else if (gidx < 2 * WT_T + 24576 + 65536 + 81920) {
        const int idx = gidx - (2 * WT_T + 24576 + 65536);
        const int i = idx & 4095, d = i >> 6, c = i & 63;
        WscT[idx] = f2bf(Wsc[(idx >> 12) * 4096 + c * 64 + d]);
    }
}

// ---------------- lin_up GEMM (MFMA) on bf16 F; l==0 folds q*qc update ----------------
__global__ __launch_bounds__(256) void k_lgemm_hb(unsigned short* __restrict__ Fb,
    const float* __restrict__ q, const float* __restrict__ qc,
    const unsigned short* __restrict__ WT, unsigned short* __restrict__ Hb)
{
    __shared__ unsigned short Xb[64 * HS];
    __shared__ unsigned short Wt[64 * HS];
    const int l  = blockIdx.y;
    const int nb = blockIdx.x << 6;
    const int t  = threadIdx.x;
    const int lane = t & 63;
    const int m0   = (t >> 6) << 4;
    const int quad = lane >> 4;
    const int idx  = lane & 15;
    const int prow = t >> 2, pkb = (t & 3) << 4;
    unsigned short* Xp = Fb + (size_t)l * NC + (size_t)nb * 64;
    if (l == 0) {
        const float qn = q[nb + prow];
        u16x8 x0 = *(const u16x8*)&Xp[prow * 64 + pkb];
        u16x8 x1 = *(const u16x8*)&Xp[prow * 64 + pkb + 8];
        #pragma unroll
        for (int j = 0; j < 8; ++j) {
            x0[j] = f2bf(bf2f(x0[j]) + qn * qc[pkb + j]);
            x1[j] = f2bf(bf2f(x1[j]) + qn * qc[pkb + 8 + j]);
        }
        *(u16x8*)&Xp[prow * 64 + pkb]     = x0;
        *(u16x8*)&Xp[prow * 64 + pkb + 8] = x1;
        *(u16x8*)&Xb[prow * HS + pkb]     = x0;
        *(u16x8*)&Xb[prow * HS + pkb + 8] = x1;
    } else {
        *(u16x8*)&Xb[prow * HS + pkb]     = *(const u16x8*)&Xp[prow * 64 + pkb];
        *(u16x8*)&Xb[prow * HS + pkb + 8] = *(const u16x8*)&Xp[prow * 64 + pkb + 8];
    }
    const unsigned short* W = WT + lmap_rt(l) * 4096;
    *(u16x8*)&Wt[prow * HS + pkb]     = *(const u16x8*)&W[prow * 64 + pkb];
    *(u16x8*)&Wt[prow * HS + pkb + 8] = *(const u16x8*)&W[prow * 64 + pkb + 8];
    __syncthreads();
    f32x4v acc[4];
    #pragma unroll
    for (int c = 0; c < 4; ++c) { acc[c][0] = 0.f; acc[c][1] = 0.f; acc[c][2] = 0.f; acc[c][3] = 0.f; }
    mfma_stage(Xb, Wt, m0, lane, acc, false);
    #pragma unroll
    for (int c4 = 0; c4 < 4; ++c4) {
        #pragma unroll
        for (int r = 0; r < 4; ++r) {
            const int n = nb + m0 + (quad << 2) + r;
            const int col = (c4 << 4) + idx;
            Hb[(size_t)n * 1024 + (l << 6) + col] = f2bf(acc[c4][r]);
        }
    }
}

// ---------------- transpose Hb[n][l][64] -> HbT[n][64][16] ----------------
__global__ __launch_bounds__(256) void k_hbT(const unsigned short* __restrict__ Hb,
    unsigned short* __restrict__ HbT)
{
    const int n = (blockIdx.x << 2) + (threadIdx.x >> 6);
    const int c = threadIdx.x & 63;
    u16x8 a, b;
    #pragma unroll
    for (int l = 0; l < 8; ++l) {
        a[l] = Hb[(size_t)n * 1024 + (l << 6) + c];
        b[l] = Hb[(size_t)n * 1024 + ((l + 8) << 6) + c];
    }
    *(u16x8*)&HbT[(size_t)n * 1024 + c * 16]     = a;
    *(u16x8*)&HbT[(size_t)n * 1024 + c * 16 + 8] = b;
}

// ---------------- lin_out GEMM (MFMA): A fp32 -> H2 bf16 ----------------
__global__ __launch_bounds__(256) void k_lgemm(const float* __restrict__ X,
    const unsigned short* __restrict__ WT, unsigned short* __restrict__ H2b)
{
    __shared__ unsigned short Xb[64 * HS];
    __shared__ unsigned short Wt[64 * HS];
    const int l  = blockIdx.y;
    const int nb = blockIdx.x << 6;
    const int t  = threadIdx.x;
    const int lane = t & 63;
    const int m0   = (t >> 6) << 4;
    const int quad = lane >> 4;
    const int idx  = lane & 15;
    const int prow = t >> 2, pkb = (t & 3) << 4;
    const float* Xp = X + (size_t)l * NC + (size_t)nb * 64;
    #pragma unroll
    for (int k = 0; k < 16; ++k) {
        const int i = t + (k << 8);
        Xb[(i >> 6) * HS + (i & 63)] = f2bf(Xp[i]);
    }
    const unsigned short* W = WT + lmap_rt(l) * 4096;
    *(u16x8*)&Wt[prow * HS + pkb]     = *(const u16x8*)&W[prow * 64 + pkb];
    *(u16x8*)&Wt[prow * HS + pkb + 8] = *(const u16x8*)&W[prow * 64 + pkb + 8];
    __syncthreads();
    f32x4v acc[4];
    #pragma unroll
    for (int c = 0; c < 4; ++c) { acc[c][0] = 0.f; acc[c][1] = 0.f; acc[c][2] = 0.f; acc[c][3] = 0.f; }
    mfma_stage(Xb, Wt, m0, lane, acc, false);
    unsigned short* Op = H2b + (size_t)l * NC + (size_t)nb * 64;
    #pragma unroll
    for (int c4 = 0; c4 < 4; ++c4) {
        #pragma unroll
        for (int r = 0; r < 4; ++r) {
            const int row = m0 + (quad << 2) + r;
            Op[(row << 6) + (c4 << 4) + idx] = f2bf(acc[c4][r]);
        }
    }
}

// ---------------- sc GEMM over element buckets (MFMA): Fb bf16 -> scb bf16 ----------------
__global__ __launch_bounds__(256) void k_sc(const unsigned short* __restrict__ Fb,
    const unsigned short* __restrict__ WscT, const int* __restrict__ perm,
    const int* __restrict__ elem, unsigned short* __restrict__ scb)
{
    __shared__ unsigned short Xb[64 * HS];
    __shared__ unsigned short Wt[64 * HS];
    __shared__ int rows[64];
    const int l  = blockIdx.y;
    const int tb = blockIdx.x << 6;
    const int t  = threadIdx.x;
    if (t < 64) rows[t] = perm[tb + t];
    __syncthreads();
    if (rows[0] < 0) return;
    const int lane = t & 63;
    const int m0   = (t >> 6) << 4;
    const int quad = lane >> 4;
    const int idx  = lane & 15;
    const int prow = t >> 2, pkb = (t & 3) << 4;
    const unsigned short* W = WscT + elem[rows[0]] * 4096;
    *(u16x8*)&Wt[prow * HS + pkb]     = *(const u16x8*)&W[prow * 64 + pkb];
    *(u16x8*)&Wt[prow * HS + pkb + 8] = *(const u16x8*)&W[prow * 64 + pkb + 8];
    {
        const int n = rows[prow];
        u16x8 z;
        #pragma unroll
        for (int j = 0; j < 8; ++j) z[j] = 0;
        u16x8 x0 = z, x1 = z;
        if (n >= 0) {
            const unsigned short* src = Fb + (size_t)l * NC + (size_t)n * 64 + pkb;
            x0 = *(const u16x8*)&src[0];
            x1 = *(const u16x8*)&src[8];
        }
        *(u16x8*)&Xb[prow * HS + pkb]     = x0;
        *(u16x8*)&Xb[prow * HS + pkb + 8] = x1;
    }
    __syncthreads();
    f32x4v acc[4];
    #pragma unroll
    for (int c = 0; c < 4; ++c) { acc[c][0] = 0.f; acc[c][1] = 0.f; acc[c][2] = 0.f; acc[c][3] = 0.f; }
    mfma_stage(Xb, Wt, m0, lane, acc, false);
    #pragma unroll
    for (int c4 = 0; c4 < 4; ++c4) {
        #pragma unroll
        for (int r = 0; r < 4; ++r) {
            const int n = rows[m0 + (quad << 2) + r];
            if (n >= 0) scb[(size_t)l * NC + (size_t)n * 64 + (c4 << 4) + idx] = f2bf(acc[c4][r]);
        }
    }
}

// ---------------- fused edge MLP + aggregation (Y regs, tree-se, pipelined LDS) ----------------
__global__ __launch_bounds__(256) void k_edge(const float4* __restrict__ geomv,
    const int* __restrict__ spck, const unsigned short* __restrict__ WT,
    const unsigned short* __restrict__ HbT, const int* __restrict__ roff,
    float* __restrict__ A)
{
    __shared__ unsigned short hbf[64 * HS];
    __shared__ unsigned short wtb[64 * HS];
    __shared__ unsigned short wfull[64 * WS2];
    __shared__ int   sps[64];
    __shared__ int   rinfo[2];
    const int t = threadIdx.x;
    const int lane = t & 63;
    const int wid  = t >> 6;
    const int m0   = wid << 4;
    const int quad = lane >> 4;
    const int idx  = lane & 15;
    const int prow = t >> 2, pkb = (t & 3) << 4;
    const int w0 = blockIdx.x << 6;
    const int w1 = w0 + 64;
    if (t == 0) {
        int lo = 0, hi = N - 1;
        while (lo < hi) { const int mid = (lo + hi + 1) >> 1; if (roff[mid] <= w0) lo = mid; else hi = mid - 1; }
        rinfo[0] = lo;
    } else if (t == 1) {
        const int w1m = w0 + 63;
        int lo = 0, hi = N - 1;
        while (lo < hi) { const int mid = (lo + hi + 1) >> 1; if (roff[mid] <= w1m) lo = mid; else hi = mid - 1; }
        rinfo[1] = lo;
    }
    // per-lane Y for edge w0+lane (all waves; zeroed beyond RMAX)
    float yreg[16];
    {
        const float4 g = geomv[w0 + lane];
        const float x = g.x, y = g.y, z = g.z;
        const float xx = x * x, yy = y * y, zz = z * z;
        yreg[0] = 1.f;
        yreg[1] = 1.7320508f * x;  yreg[2] = 1.7320508f * y;  yreg[3] = 1.7320508f * z;
        yreg[4] = 3.8729833f * x * y;  yreg[5] = 3.8729833f * y * z;
        yreg[6] = 0.5f * 2.2360680f * (3.f * zz - 1.f);
        yreg[7] = 3.8729833f * x * z;  yreg[8] = 0.5f * 3.8729833f * (xx - yy);
        yreg[9]  = 2.0916500f * y * (3.f * xx - yy);
        yreg[10] = 10.2469508f * x * y * z;
        yreg[11] = 1.6201852f * y * (5.f * zz - 1.f);
        yreg[12] = 0.5f * 2.6457513f * z * (5.f * zz - 3.f);
        yreg[13] = 1.6201852f * x * (5.f * zz - 1.f);
        yreg[14] = 0.5f * 10.2469508f * z * (xx - yy);
        yreg[15] = 2.0916500f * x * (xx - 3.f * yy);
        const float m = (g.w < RMAX) ? 1.f : 0.f;
        #pragma unroll
        for (int l = 0; l < 16; ++l) yreg[l] *= m;
        if (t < 64) {
            sps[t] = spck[w0 + t];
            const float r = g.w;
            const float u  = r * 0.2f;
            const float u2 = u * u, u5 = u2 * u2 * u;
            const float fc = 1.f - 21.f * u5 + 35.f * u5 * u - 15.f * u5 * u2;
            float pref = 0.63245553f * fc / (r + 1e-9f);
            if (u >= 1.f) pref = 0.f;
            const float piu = 3.14159265358979f * u;
            #pragma unroll
            for (int b = 0; b < 8; ++b) hbf[t * HS + b] = f2bf(__sinf((float)(b + 1) * piu) * pref);
        }
    }
    {
        const int n = t >> 2, k = (t & 3) << 1;
        wtb[n * HS + k]     = WT[n * 8 + k];
        wtb[n * HS + k + 1] = WT[n * 8 + k + 1];
    }
    u16x8 pf0 = *(const u16x8*)&WT[512 + prow * 64 + pkb];
    u16x8 pf1 = *(const u16x8*)&WT[512 + prow * 64 + pkb + 8];
    __syncthreads();
    f32x4v acc[4];
    #pragma unroll
    for (int c = 0; c < 4; ++c) { acc[c][0] = 0.f; acc[c][1] = 0.f; acc[c][2] = 0.f; acc[c][3] = 0.f; }
    mfma_stage(hbf, wtb, m0, lane, acc, true);
    __syncthreads();
    #pragma unroll
    for (int c4 = 0; c4 < 4; ++c4)
        #pragma unroll
        for (int r = 0; r < 4; ++r)
            hbf[(m0 + (quad << 2) + r) * HS + (c4 << 4) + idx] = f2bf(silu(acc[c4][r]));
    *(u16x8*)&wtb[prow * HS + pkb]     = pf0;
    *(u16x8*)&wtb[prow * HS + pkb + 8] = pf1;
    pf0 = *(const u16x8*)&WT[4608 + prow * 64 + pkb];
    pf1 = *(const u16x8*)&WT[4608 + prow * 64 + pkb + 8];
    __syncthreads();
    #pragma unroll
    for (int c = 0; c < 4; ++c) { acc[c][0] = 0.f; acc[c][1] = 0.f; acc[c][2] = 0.f; acc[c][3] = 0.f; }
    mfma_stage(hbf, wtb, m0, lane, acc, false);
    __syncthreads();
    #pragma unroll
    for (int c4 = 0; c4 < 4; ++c4)
        #pragma unroll
        for (int r = 0; r < 4; ++r)
            hbf[(m0 + (quad << 2) + r) * HS + (c4 << 4) + idx] = f2bf(silu(acc[c4][r]));
    *(u16x8*)&wtb[prow * HS + pkb]     = pf0;
    *(u16x8*)&wtb[prow * HS + pkb + 8] = pf1;
    pf0 = *(const u16x8*)&WT[8704 + prow * 64 + pkb];
    pf1 = *(const u16x8*)&WT[8704 + prow * 64 + pkb + 8];
    __syncthreads();
    #pragma unroll
    for (int c = 0; c < 4; ++c) { acc[c][0] = 0.f; acc[c][1] = 0.f; acc[c][2] = 0.f; acc[c][3] = 0.f; }
    mfma_stage(hbf, wtb, m0, lane, acc, false);
    __syncthreads();
    #pragma unroll
    for (int c4 = 0; c4 < 4; ++c4)
        #pragma unroll
        for (int r = 0; r < 4; ++r)
            hbf[(m0 + (quad << 2) + r) * HS + (c4 << 4) + idx] = f2bf(silu(acc[c4][r]));
    *(u16x8*)&wtb[prow * HS + pkb]     = pf0;
    *(u16x8*)&wtb[prow * HS + pkb + 8] = pf1;
    pf0 = *(const u16x8*)&WT[8704 + 4096 + prow * 64 + pkb];
    pf1 = *(const u16x8*)&WT[8704 + 4096 + prow * 64 + pkb + 8];
    __syncthreads();
    for (int cc = 0; cc < 4; ++cc) {
        #pragma unroll
        for (int c = 0; c < 4; ++c) { acc[c][0] = 0.f; acc[c][1] = 0.f; acc[c][2] = 0.f; acc[c][3] = 0.f; }
        mfma_stage(hbf, wtb, m0, lane, acc, false);
        __syncthreads();
        #pragma unroll
        for (int c4 = 0; c4 < 4; ++c4)
            #pragma unroll
            for (int r = 0; r < 4; ++r)
                wfull[(m0 + (quad << 2) + r) * WS2 + (cc << 6) + (c4 << 4) + idx] = f2bf(acc[c4][r]);
        if (cc < 3) {
            *(u16x8*)&wtb[prow * HS + pkb]     = pf0;
            *(u16x8*)&wtb[prow * HS + pkb + 8] = pf1;
            if (cc < 2) {
                pf0 = *(const u16x8*)&WT[8704 + (cc + 2) * 4096 + prow * 64 + pkb];
                pf1 = *(const u16x8*)&WT[8704 + (cc + 2) * 4096 + prow * 64 + pkb + 8];
            }
        }
        __syncthreads();
    }
    const int r0 = rinfo[0], r1 = rinfo[1];
    constexpr int LM[16] = {0,1,1,1,2,2,2,2,2,3,3,3,3,3,3,3};
    for (int r = r0 + wid; r <= r1; r += 4) {
        const int ra = roff[r], rb = roff[r + 1];
        const int ja = ra > w0 ? ra : w0;
        const int jb = rb < w1 ? rb : w1;
        float a16[16];
        #pragma unroll
        for (int l = 0; l < 16; ++l) a16[l] = 0.f;
        if (ja < jb) {
            u16x8 hA0, hB0, hA1, hB1;
            ushort4 wq0, wq1;
            {
                const int s = sps[ja - w0];
                hA0 = *(const u16x8*)&HbT[(size_t)s * 1024 + lane * 16];
                hB0 = *(const u16x8*)&HbT[(size_t)s * 1024 + lane * 16 + 8];
                wq0 = *(const ushort4*)&wfull[(ja - w0) * WS2 + (lane << 2)];
            }
            hA1 = hA0; hB1 = hB0; wq1 = wq0;
            if (ja + 1 < jb) {
                const int s = sps[ja + 1 - w0];
                hA1 = *(const u16x8*)&HbT[(size_t)s * 1024 + lane * 16];
                hB1 = *(const u16x8*)&HbT[(size_t)s * 1024 + lane * 16 + 8];
                wq1 = *(const ushort4*)&wfull[(ja + 1 - w0) * WS2 + (lane << 2)];
            }
            for (int j = ja; j < jb; ++j) {
                const int jj = j - w0;
                float hc[16];
                #pragma unroll
                for (int l = 0; l < 8; ++l) { hc[l] = bf2f(hA0[l]); hc[l + 8] = bf2f(hB0[l]); }
                const ushort4 wq = wq0;
                hA0 = hA1; hB0 = hB1; wq0 = wq1;
                if (j + 2 < jb) {
                    const int jn = jj + 2;
                    const int s = sps[jn];
                    hA1 = *(const u16x8*)&HbT[(size_t)s * 1024 + lane * 16];
                    hB1 = *(const u16x8*)&HbT[(size_t)s * 1024 + lane * 16 + 8];
                    wq1 = *(const ushort4*)&wfull[jn * WS2 + (lane << 2)];
                }
                // broadcast edge jj's Y from lane jj (jj is wave-uniform)
                float sY[16];
                #pragma unroll
                for (int l = 0; l < 16; ++l) sY[l] = rdlane(yreg[l], jj);
                // 4-way tree reduction for se (breaks serial FMA chain)
                float se0 = 0.f, se1 = 0.f, se2 = 0.f, se3 = 0.f;
                #pragma unroll
                for (int l = 0; l < 16; l += 4) {
                    se0 += hc[l]     * sY[l];
                    se1 += hc[l + 1] * sY[l + 1];
                    se2 += hc[l + 2] * sY[l + 2];
                    se3 += hc[l + 3] * sY[l + 3];
                }
                const float se = ((se0 + se1) + (se2 + se3)) * 0.0625f;
                const float wl[4] = { bf2f(wq.x) * se, bf2f(wq.y) * se, bf2f(wq.z) * se, bf2f(wq.w) * se };
                #pragma unroll
                for (int l = 0; l < 16; ++l) a16[l] += wl[LM[l]] * sY[l];
            }
        }
        float* Ap = A + (size_t)r * 64 + lane;
        if (ra >= w0 && rb <= w1) {
            #pragma unroll
            for (int l = 0; l < 16; ++l) Ap[(size_t)l * NC] = a16[l];
        } else {
            #pragma unroll
            for (int l = 0; l < 16; ++l) atomicAdd(&Ap[(size_t)l * NC], a16[l]);
        }
    }
}

// ---------------- s1[n][c] = sum_l H2[l][n][c]^2 (bf16 in) ----------------
__global__ __launch_bounds__(256) void k_s1(const unsigned short* __restrict__ H2b, float* __restrict__ s1)
{
    const int i = blockIdx.x * 256 + threadIdx.x;
    if (i < NC) {
        float s = 0.f;
        #pragma unroll
        for (int l = 0; l < 16; ++l) { const float a = bf2f(H2b[(size_t)l * NC + i]); s += a * a; }
        s1[i] = s;
    }
}

// ---------------- out = sum_p (A'*s1^p)@Wp_p + sc -> Fb  (MFMA, bf16 state) ----------------
__global__ __launch_bounds__(256) void k_out(const unsigned short* __restrict__ H2b,
    const float* __restrict__ s1, const unsigned short* __restrict__ WpT,
    const unsigned short* __restrict__ scb, unsigned short* __restrict__ Fb)
{
    __shared__ unsigned short Xb[64 * HS];
    __shared__ unsigned short Wt[64 * HS];
    const int l  = blockIdx.y;
    const int nb = blockIdx.x << 6;
    const int t  = threadIdx.x;
    const int lane = t & 63;
    const int m0   = (t >> 6) << 4;
    const int quad = lane >> 4;
    const int idx  = lane & 15;
    const int prow = t >> 2, pkb = (t & 3) << 4;
    const unsigned short* Xp = H2b + (size_t)l * NC + (size_t)nb * 64;
    float av[16], sv[16];
    {
        const u16x8 x0 = *(const u16x8*)&Xp[prow * 64 + pkb];
        const u16x8 x1 = *(const u16x8*)&Xp[prow * 64 + pkb + 8];
        #pragma unroll
        for (int j = 0; j < 8; ++j) { av[j] = bf2f(x0[j]); av[8 + j] = bf2f(x1[j]); }
        #pragma unroll
        for (int j = 0; j < 4; ++j) {
            const float4 s4 = *(const float4*)&s1[(nb + prow) * 64 + pkb + (j << 2)];
            sv[j * 4] = s4.x; sv[j * 4 + 1] = s4.y; sv[j * 4 + 2] = s4.z; sv[j * 4 + 3] = s4.w;
        }
    }
    f32x4v acc[4];
    #pragma unroll
    for (int c = 0; c < 4; ++c) { acc[c][0] = 0.f; acc[c][1] = 0.f; acc[c][2] = 0.f; acc[c][3] = 0.f; }
    for (int p = 0; p < 3; ++p) {
        u16x8 x0, x1;
        #pragma unroll
        for (int j = 0; j < 8; ++j) { x0[j] = f2bf(av[j]); x1[j] = f2bf(av[8 + j]); }
        *(u16x8*)&Xb[prow * HS + pkb]     = x0;
        *(u16x8*)&Xb[prow * HS + pkb + 8] = x1;
        #pragma unroll
        for (int k = 0; k < 16; ++k) av[k] *= sv[k];
        *(u16x8*)&Wt[prow * HS + pkb]     = *(const u16x8*)&WpT[p * 4096 + prow * 64 + pkb];
        *(u16x8*)&Wt[prow * HS + pkb + 8] = *(const u16x8*)&WpT[p * 4096 + prow * 64 + pkb + 8];
        __syncthreads();
        mfma_stage(Xb, Wt, m0, lane, acc, false);
        __syncthreads();
    }
    #pragma unroll
    for (int c4 = 0; c4 < 4; ++c4) {
        #pragma unroll
        for (int r = 0; r < 4; ++r) {
            const int row = m0 + (quad << 2) + r;
            const int col = (c4 << 4) + idx;
            const size_t id = (size_t)l * NC + (size_t)(nb + row) * 64 + col;
            Fb[id] = f2bf(acc[c4][r] + bf2f(scb[id]));
        }
    }
}

// ---------------- readout (bf16 F) ----------------
__global__ __launch_bounds__(256) void k_read(const unsigned short* __restrict__ Fb,
    const float* __restrict__ q, const int* __restrict__ batch,
    const float* __restrict__ Wr0, const float* __restrict__ Wa,
    const float* __restrict__ Wb, const float* __restrict__ Wq,
    float* __restrict__ acc, int last)
{
    __shared__ float sred[G];
    if (threadIdx.x < G) sred[threadIdx.x] = 0.f;
    __syncthreads();
    const int n = blockIdx.x * 256 + threadIdx.x;
    if (n < N) {
        float a16[16];
        #pragma unroll
        for (int j = 0; j < 16; ++j) a16[j] = 0.f;
        float ar = 0.f, aq = 0.f;
        const unsigned short* f = Fb + (size_t)n * 64;
        for (int c = 0; c < 64; ++c) {
            const float fv = bf2f(f[c]);
            aq += fv * Wq[c];
            if (last) {
                #pragma unroll
                for (int j = 0; j < 16; ++j) a16[j] += fv * Wa[c * 16 + j];
            } else ar += fv * Wr0[c];
        }
        float en;
        if (last) {
            en = 0.f;
            #pragma unroll
            for (int j = 0; j < 16; ++j) en += silu(a16[j]) * Wb[j];
        } else en = ar;
        en += q[n] * aq;
        atomicAdd(&sred[batch[n]], en);
    }
    __syncthreads();
    if (threadIdx.x < G) atomicAdd(&acc[threadIdx.x * 5], sred[threadIdx.x]);
}

// ---------------- Ewald ----------------
__global__ __launch_bounds__(256) void k_kvec(const float* __restrict__ rcell,
    float* __restrict__ kvec, float* __restrict__ k2)
{
    const int idx = blockIdx.x * 256 + threadIdx.x;
    if (idx >= G * NK) return;
    const int g = idx / NK, k = idx % NK;
    const int kk = k + (k >= 171 ? 1 : 0);
    const int a = kk / 49 - 3, b = (kk / 7) % 7 - 3, c = kk % 7 - 3;
    const float* rc = rcell + g * 9;
    float s = 0.f;
    #pragma unroll
    for (int i = 0; i < 3; ++i) {
        const float kv = 6.283185307f * ((float)a * rc[0 + i] + (float)b * rc[3 + i] + (float)c * rc[6 + i]);
        kvec[idx * 3 + i] = kv;
        s += kv * kv;
    }
    k2[idx] = s;
}

__global__ __launch_bounds__(256) void k_phase(const float* __restrict__ pos,
    const float* __restrict__ q, const float* __restrict__ kvec,
    float* __restrict__ Sr, float* __restrict__ Si)
{
    __shared__ float kvs[38 * 3];
    __shared__ float srs[38], sis[38];
    const int g = blockIdx.z, kc = blockIdx.x, ncb = blockIdx.y;
    const int kbase = kc * 38;
    if (threadIdx.x < 38 * 3) kvs[threadIdx.x] = kvec[((size_t)g * NK + kbase) * 3 + threadIdx.x];
    if (threadIdx.x < 38) { srs[threadIdx.x] = 0.f; sis[threadIdx.x] = 0.f; }
    __syncthreads();
    const int t = threadIdx.x;
    float px = 0.f, py = 0.f, pz = 0.f, qn = 0.f;
    if (t < 250) {
        const int n = g * NGR + ncb * 250 + t;
        px = pos[n * 3]; py = pos[n * 3 + 1]; pz = pos[n * 3 + 2]; qn = q[n];
    }
    const int lane = t & 63;
    for (int j = 0; j < 38; ++j) {
        const float ph = px * kvs[j * 3] + py * kvs[j * 3 + 1] + pz * kvs[j * 3 + 2];
        float sv, cv;
        __sincosf(ph, &sv, &cv);
        float vr = qn * cv, vi = qn * sv;
        #pragma unroll
        for (int o = 32; o > 0; o >>= 1) { vr += __shfl_down(vr, o, 64); vi += __shfl_down(vi, o, 64); }
        if (lane == 0) { atomicAdd(&srs[j], vr); atomicAdd(&sis[j], vi); }
    }
    __syncthreads();
    if (t < 38) {
        atomicAdd(&Sr[g * NK + kbase + t], srs[t]);
        atomicAdd(&Si[g * NK + kbase + t], sis[t]);
    }
}

__global__ __launch_bounds__(512) void k_final(const float* __restrict__ k2,
    const float* __restrict__ Sr, const float* __restrict__ Si,
    const float* __restrict__ vol, const float* __restrict__ acc,
    float* __restrict__ out)
{
    __shared__ float red[512];
    const int g = blockIdx.x, t = threadIdx.x;
    float v = 0.f;
    if (t < NK) {
        const float kk = k2[g * NK + t];
        const float sr = Sr[g * NK + t], si = Si[g * NK + t];
        v = __expf(-0.5f * kk) * (sr * sr + si * si) / kk;
    }
    red[t] = v;
    __syncthreads();
    for (int s2 = 256; s2 > 0; s2 >>= 1) {
        if (t < s2) red[t] += red[t + s2];
        __syncthreads();
    }
    if (t == 0) {
        const float Ees = 6.283185307f / vol[g] * red[0];
        out[g]     = acc[g * 5 + 0] + Ees;
        out[4 + g] = acc[g * 5 + 1];
        out[8 + g * 3 + 0] = acc[g * 5 + 2];
        out[8 + g * 3 + 1] = acc[g * 5 + 3];
        out[8 + g * 3 + 2] = acc[g * 5 + 4];
    }
}

extern "C" void kernel_launch(void* const* d_in, const int* in_sizes, int n_in,
                              void* d_out, int out_size, void* d_ws, size_t ws_size,
                              hipStream_t stream)
{
    const float* na    = (const float*)d_in[0];
    const float* pos   = (const float*)d_in[1];
    const float* shif  = (const float*)d_in[2];
    const float* q     = (const float*)d_in[3];
    const float* rcell = (const float*)d_in[5];
    const float* vol   = (const float*)d_in[6];
    const int*   ei    = (const int*)d_in[7];
    const int*   batch = (const int*)d_in[8];
    const float* embW  = (const float*)d_in[9];
    const float* qcoef = (const float*)d_in[10];
    const float* rW1   = (const float*)d_in[11];
    const float* rW2   = (const float*)d_in[12];
    const float* rW3   = (const float*)d_in[13];
    const float* rW4   = (const float*)d_in[14];
    const float* lup   = (const float*)d_in[15];
    const float* lout  = (const float*)d_in[16];
    const float* Wsc   = (const float*)d_in[17];
    const float* Wp    = (const float*)d_in[18];
    const float* Wr0   = (const float*)d_in[19];
    const float* Wa    = (const float*)d_in[20];
    const float* Wb    = (const float*)d_in[21];
    const float* Wq    = (const float*)d_in[22];
    const float* aE    = (const float*)d_in[23];
    float* out = (float*)d_out;

    float* wsf  = (float*)d_ws;
    unsigned short* Fb = (unsigned short*)wsf;           // bf16 [16][N][64]
    float* A    = wsf + 8192000;        // [16][N][64] fp32 (agg out); later aliased as scb bf16
    unsigned short* scb = (unsigned short*)A;            // bf16 [16][N][64]
    float* R    = A + 8192000;
    unsigned short* H2b   = (unsigned short*)R;              // bf16 [16][N][64]
    unsigned short* HbT   = (unsigned short*)R;              // bf16 [N][64][16]
    unsigned short* Hbtmp = (unsigned short*)(R + 4096000);  // bf16 [N][16][64] (transient)
    float* s1   = R + 20480000;         // [N][64]
    float* kvec = s1 + 512000;          // [G*342][3]
    float* k2   = kvec + 4104;
    float* Sr   = k2 + 1368;
    float* Si   = Sr + 1368;
    float* acc  = Si + 1368;            // [G][5]
    int*   elem = (int*)(acc + 32);     // [N]
    int*   perm = elem + 8000;          // [8640]
    int*   counts = perm + 8640;        // [16]
    int*   cursor = counts + 16;        // [16]
    int*   offs   = cursor + 16;        // [16]
    int*   roff   = offs + 16;          // [N+1]
    int*   cnt    = roff + 8001;        // [N]
    int*   cur    = cnt + 8000;         // [N]
    int*   elist  = cur + 8000;         // [E]
    unsigned short* WTb = (unsigned short*)(((uintptr_t)(elist + E) + 31) & ~(uintptr_t)31); // [2*WT_T]
    unsigned short* WpT = WTb + 2 * WT_T;                // [24576]
    float4* geomv = (float4*)(WpT + 24576);              // [E]
    int*    spck  = (int*)(geomv + E);                   // [E]
    unsigned short* WlupT  = (unsigned short*)(spck + E); // [32768]
    unsigned short* WloutT = WlupT + 32768;               // [32768]
    unsigned short* WscT   = WloutT + 32768;              // [81920]

    hipMemsetAsync(Fb, 0, 8192000 * sizeof(unsigned short), stream);
    hipMemsetAsync(Sr, 0, (1368 * 2 + 32) * sizeof(float), stream);
    hipMemsetAsync(perm, 0xFF, 8640 * sizeof(int), stream);
    hipMemsetAsync(counts, 0, 32 * sizeof(int), stream);
    hipMemsetAsync(cnt, 0, 16000 * sizeof(int), stream);

    k_init<<<32, 256, 0, stream>>>(na, q, pos, batch, aE, elem, counts, acc);
    k_feat0<<<2000, 256, 0, stream>>>(elem, embW, Fb);
    k_offs<<<1, 64, 0, stream>>>(counts, offs);
    k_scatter<<<32, 256, 0, stream>>>(elem, offs, cursor, perm);
    k_gcnt<<<500, 256, 0, stream>>>(ei, cnt);
    k_goff<<<1, 1024, 0, stream>>>(cnt, roff);
    k_gscat<<<500, 256, 0, stream>>>(ei, roff, cur, elist);
    k_geom<<<500, 256, 0, stream>>>(pos, shif, ei, elist, geomv, spck);
    k_wprep_all<<<868, 256, 0, stream>>>(rW1, rW2, rW3, rW4, Wp, lup, lout, Wsc,
                                         WTb, WpT, WlupT, WloutT, WscT);
    k_kvec<<<6, 256, 0, stream>>>(rcell, kvec, k2);
    k_phase<<<dim3(9, 8, G), 256, 0, stream>>>(pos, q, kvec, Sr, Si);

    for (int t = 0; t < 2; ++t) {
        k_lgemm_hb<<<dim3(125, 16), 256, 0, stream>>>(Fb, q, qcoef + t * 64, WlupT + t * 16384, Hbtmp);
        k_hbT<<<2000, 256, 0, stream>>>(Hbtmp, HbT);
        hipMemsetAsync(A, 0, 8192000 * sizeof(float), stream);
        k_edge<<<2000, 256, 0, stream>>>(geomv, spck, WTb + t * WT_T, HbT, roff, A);
        k_lgemm<<<dim3(125, 16), 256, 0, stream>>>(A, WloutT + t * 16384, H2b);
        k_s1<<<2000, 256, 0, stream>>>(H2b, s1);
        k_sc<<<dim3(135, 16), 256, 0, stream>>>(Fb, WscT + t * 40960, perm, elem, scb);
        k_out<<<dim3(125, 16), 256, 0, stream>>>(H2b, s1, WpT + t * 12288, scb, Fb);
        k_read<<<32, 256, 0, stream>>>(Fb, q, batch, Wr0, Wa, Wb, Wq + t * 64, acc, t == 1);
    }
    k_final<<<G, 512, 0, stream>>>(k2, Sr, Si, vol, acc, out);
}

// Round 14
// 528.150 us; speedup vs baseline: 1.0451x; 1.0157x over previous
//
#include <hip/hip_runtime.h>
#include <hip/hip_bf16.h>

constexpr int N    = 8000;
constexpr int E    = 128000;
constexpr int G    = 4;
constexpr int NEL  = 10;
constexpr int NGR  = N / G;          // 2000
constexpr int NC   = N * 64;         // 512000
constexpr int NK   = 342;            // Ewald vectors
constexpr float RMAX = 5.0f;
constexpr int HS = 72;               // padded LDS row stride (bf16) for MFMA tiles
constexpr int WS2 = 260;             // wfull row stride (ushorts)
constexpr int WT_T = 25088;          // per-t size of transposed radial-weight block (ushorts)

typedef __bf16 bf16x8 __attribute__((ext_vector_type(8)));
typedef float  f32x4v __attribute__((ext_vector_type(4)));
typedef unsigned short u16x8 __attribute__((ext_vector_type(8)));

__device__ __forceinline__ int lmap_rt(int l) { return (l >= 1) + (l >= 4) + (l >= 9); }
__device__ __forceinline__ float silu(float x) { return x / (1.f + __expf(-x)); }
__device__ __forceinline__ float bf2f(unsigned short u) { return __uint_as_float(((unsigned)u) << 16); }
__device__ __forceinline__ unsigned short f2bf(float f) {
    __hip_bfloat16 h = __float2bfloat16(f);
    return *(unsigned short*)&h;
}

// MFMA 64x64(xK) stage: hsrc rows = M (stride HS), wt rows = N (stride HS), K=64 (or 8)
__device__ __forceinline__ void mfma_stage(const unsigned short* hsrc, const unsigned short* wt,
                                           int m0, int lane, f32x4v acc[4], bool k8only)
{
    const int quad = lane >> 4;
    const int idx  = lane & 15;
    bf16x8 bz;
    #pragma unroll
    for (int i = 0; i < 8; ++i) bz[i] = (__bf16)0.f;
    bf16x8 a0 = bz, a1 = bz;
    const int mrow = m0 + idx;
    if (k8only) {
        if (quad == 0) a0 = *(const bf16x8*)&hsrc[mrow * HS];
    } else {
        a0 = *(const bf16x8*)&hsrc[mrow * HS + (quad << 3)];
        a1 = *(const bf16x8*)&hsrc[mrow * HS + 32 + (quad << 3)];
    }
    #pragma unroll
    for (int c4 = 0; c4 < 4; ++c4) {
        const int nrow = (c4 << 4) + idx;
        if (k8only) {
            bf16x8 b0 = bz;
            if (quad == 0) b0 = *(const bf16x8*)&wt[nrow * HS];
            acc[c4] = __builtin_amdgcn_mfma_f32_16x16x32_bf16(a0, b0, acc[c4], 0, 0, 0);
        } else {
            const bf16x8 b0 = *(const bf16x8*)&wt[nrow * HS + (quad << 3)];
            const bf16x8 b1 = *(const bf16x8*)&wt[nrow * HS + 32 + (quad << 3)];
            acc[c4] = __builtin_amdgcn_mfma_f32_16x16x32_bf16(a0, b0, acc[c4], 0, 0, 0);
            acc[c4] = __builtin_amdgcn_mfma_f32_16x16x32_bf16(a1, b1, acc[c4], 0, 0, 0);
        }
    }
}

// ---------------- init: elem, hist, e0/charge/dipole ----------------
__global__ __launch_bounds__(256) void k_init(const float* __restrict__ na,
    const float* __restrict__ q, const float* __restrict__ pos,
    const int* __restrict__ batch, const float* __restrict__ aE,
    int* __restrict__ elem, int* __restrict__ counts, float* __restrict__ acc)
{
    __shared__ float s[G * 5];
    if (threadIdx.x < G * 5) s[threadIdx.x] = 0.f;
    __syncthreads();
    const int n = blockIdx.x * 256 + threadIdx.x;
    if (n < N) {
        int el = 0; float best = na[n * NEL];
        #pragma unroll
        for (int j = 1; j < NEL; ++j) { float v = na[n * NEL + j]; if (v > best) { best = v; el = j; } }
        elem[n] = el;
        atomicAdd(&counts[el], 1);
        const int g = batch[n];
        const float qn = q[n];
        atomicAdd(&s[g * 5 + 0], aE[el]);
        atomicAdd(&s[g * 5 + 1], qn);
        atomicAdd(&s[g * 5 + 2], qn * pos[n * 3 + 0]);
        atomicAdd(&s[g * 5 + 3], qn * pos[n * 3 + 1]);
        atomicAdd(&s[g * 5 + 4], qn * pos[n * 3 + 2]);
    }
    __syncthreads();
    if (threadIdx.x < G * 5) atomicAdd(&acc[threadIdx.x], s[threadIdx.x]);
}

__global__ __launch_bounds__(256) void k_feat0(const int* __restrict__ elem,
    const float* __restrict__ embW, unsigned short* __restrict__ Fb)
{
    const int i = blockIdx.x * 256 + threadIdx.x;
    if (i < NC) Fb[i] = f2bf(embW[elem[i >> 6] * 64 + (i & 63)]);
}

__global__ __launch_bounds__(256) void k_scatter(const int* __restrict__ elem,
    const int* __restrict__ offs, int* __restrict__ cursor, int* __restrict__ perm)
{
    const int n = blockIdx.x * 256 + threadIdx.x;
    if (n < N) {
        const int el = elem[n];
        const int p = atomicAdd(&cursor[el], 1);
        perm[offs[el] + p] = n;
    }
}

// ---------------- receiver CSR build (+element offs folded in) ----------------
__global__ __launch_bounds__(256) void k_gcnt(const int* __restrict__ ei, int* __restrict__ cnt)
{
    const int e = blockIdx.x * 256 + threadIdx.x;
    if (e < E) atomicAdd(&cnt[ei[E + e]], 1);
}
__global__ __launch_bounds__(1024) void k_goff(const int* __restrict__ cnt, int* __restrict__ roff,
    const int* __restrict__ counts, int* __restrict__ offs)
{
    __shared__ int part[1024];
    const int t = threadIdx.x;
    if (t == 0) {
        int o = 0;
        for (int j = 0; j < NEL; ++j) { offs[j] = o; o += (counts[j] + 63) & ~63; }
        offs[NEL] = o;
    }
    const int base = t * 8;
    int loc[8];
    int s = 0;
    #pragma unroll
    for (int i = 0; i < 8; ++i) { loc[i] = s; s += (base + i < N) ? cnt[base + i] : 0; }
    part[t] = s;
    __syncthreads();
    for (int d = 1; d < 1024; d <<= 1) {
        const int v = (t >= d) ? part[t - d] : 0;
        __syncthreads();
        part[t] += v;
        __syncthreads();
    }
    const int excl = (t == 0) ? 0 : part[t - 1];
    #pragma unroll
    for (int i = 0; i < 8; ++i) if (base + i < N) roff[base + i] = excl + loc[i];
    if (t == 0) roff[N] = E;
}
__global__ __launch_bounds__(256) void k_gscat(const int* __restrict__ ei,
    const int* __restrict__ roff, int* __restrict__ cur, int* __restrict__ elist)
{
    const int e = blockIdx.x * 256 + threadIdx.x;
    if (e < E) {
        const int rv = ei[E + e];
        const int p = atomicAdd(&cur[rv], 1);
        elist[roff[rv] + p] = e;
    }
}

// ---------------- per-elist-position geometry precompute ----------------
__global__ __launch_bounds__(256) void k_geom(const float* __restrict__ pos,
    const float* __restrict__ shifts, const int* __restrict__ ei,
    const int* __restrict__ elist, float4* __restrict__ geomv, int* __restrict__ spck)
{
    const int j = blockIdx.x * 256 + threadIdx.x;
    if (j >= E) return;
    const int e = elist[j];
    const int s = ei[e], rv = ei[E + e];
    const float dx = pos[rv * 3 + 0] - pos[s * 3 + 0] + shifts[e * 3 + 0];
    const float dy = pos[rv * 3 + 1] - pos[s * 3 + 1] + shifts[e * 3 + 1];
    const float dz = pos[rv * 3 + 2] - pos[s * 3 + 2] + shifts[e * 3 + 2];
    const float r = sqrtf(dx * dx + dy * dy + dz * dz);
    const float inv = 1.f / (r + 1e-9f);
    float4 g;
    g.x = dx * inv; g.y = dy * inv; g.z = dz * inv; g.w = r;
    geomv[j] = g;
    spck[j] = s;
}

// ---------------- merged weight transpose+bf16 prep (runs once) ----------------
__global__ __launch_bounds__(256) void k_wprep_all(const float* __restrict__ rW1,
    const float* __restrict__ rW2, const float* __restrict__ rW3,
    const float* __restrict__ rW4, const float* __restrict__ Wp,
    const float* __restrict__ lup, const float* __restrict__ lout,
    const float* __restrict__ Wsc,
    unsigned short* __restrict__ WT, unsigned short* __restrict__ WpT,
    unsigned short* __restrict__ WlupT, unsigned short* __restrict__ WloutT,
    unsigned short* __restrict__ WscT)
{
    const int gidx = blockIdx.x * 256 + threadIdx.x;
    if (gidx < 2 * WT_T) {
        const int t = gidx / WT_T;
        const int r = gidx % WT_T;
        float v;
        if (r < 512) {
            const int n = r >> 3, k = r & 7;
            v = rW1[t * 512 + k * 64 + n];
        } else if (r < 4608) {
            const int i = r - 512, n = i >> 6, k = i & 63;
            v = rW2[t * 4096 + k * 64 + n];
        } else if (r < 8704) {
            const int i = r - 4608, n = i >> 6, k = i & 63;
            v = rW3[t * 4096 + k * 64 + n];
        } else {
            const int i = r - 8704, n = i >> 6, k = i & 63;
            v = rW4[t * 16384 + k * 256 + n];
        }
        WT[gidx] = f2bf(v);
    } else if (gidx < 2 * WT_T + 24576) {
        const int idx = gidx - 2 * WT_T;
        const int i  = idx & 4095;
        const int d = i >> 6, c = i & 63;
        WpT[idx] = f2bf(Wp[(size_t)(idx >> 12) * 4096 + c * 64 + d]);
    } else if (gidx < 2 * WT_T + 24576 + 32768) {
        const int idx = gidx - (2 * WT_T + 24576);
        const int i = idx & 4095, d = i >> 6, c = i & 63;
        WlupT[idx] = f2bf(lup[(idx >> 12) * 4096 + c * 64 + d]);
    } else if (gidx < 2 * WT_T + 24576 + 65536) {
        const int idx = gidx - (2 * WT_T + 24576 + 32768);
        const int i = idx & 4095, d = i >> 6, c = i & 63;
        WloutT[idx] = f2bf(lout[(idx >> 12) * 4096 + c * 64 + d]);
    } else if (gidx < 2 * WT_T + 24576 + 65536 + 81920) {
        const int idx = gidx - (2 * WT_T + 24576 + 65536);
        const int i = idx & 4095, d = i >> 6, c = i & 63;
        WscT[idx] = f2bf(Wsc[(idx >> 12) * 4096 + c * 64 + d]);
    }
}

// ---------------- lin_up GEMM (MFMA) on bf16 F; l==0 folds q*qc update ----------------
__global__ __launch_bounds__(256) void k_lgemm_hb(unsigned short* __restrict__ Fb,
    const float* __restrict__ q, const float* __restrict__ qc,
    const unsigned short* __restrict__ WT, unsigned short* __restrict__ Hb)
{
    __shared__ unsigned short Xb[64 * HS];
    __shared__ unsigned short Wt[64 * HS];
    const int l  = blockIdx.y;
    const int nb = blockIdx.x << 6;
    const int t  = threadIdx.x;
    const int lane = t & 63;
    const int m0   = (t >> 6) << 4;
    const int quad = lane >> 4;
    const int idx  = lane & 15;
    const int prow = t >> 2, pkb = (t & 3) << 4;
    unsigned short* Xp = Fb + (size_t)l * NC + (size_t)nb * 64;
    if (l == 0) {
        const float qn = q[nb + prow];
        u16x8 x0 = *(const u16x8*)&Xp[prow * 64 + pkb];
        u16x8 x1 = *(const u16x8*)&Xp[prow * 64 + pkb + 8];
        #pragma unroll
        for (int j = 0; j < 8; ++j) {
            x0[j] = f2bf(bf2f(x0[j]) + qn * qc[pkb + j]);
            x1[j] = f2bf(bf2f(x1[j]) + qn * qc[pkb + 8 + j]);
        }
        *(u16x8*)&Xp[prow * 64 + pkb]     = x0;
        *(u16x8*)&Xp[prow * 64 + pkb + 8] = x1;
        *(u16x8*)&Xb[prow * HS + pkb]     = x0;
        *(u16x8*)&Xb[prow * HS + pkb + 8] = x1;
    } else {
        *(u16x8*)&Xb[prow * HS + pkb]     = *(const u16x8*)&Xp[prow * 64 + pkb];
        *(u16x8*)&Xb[prow * HS + pkb + 8] = *(const u16x8*)&Xp[prow * 64 + pkb + 8];
    }
    const unsigned short* W = WT + lmap_rt(l) * 4096;
    *(u16x8*)&Wt[prow * HS + pkb]     = *(const u16x8*)&W[prow * 64 + pkb];
    *(u16x8*)&Wt[prow * HS + pkb + 8] = *(const u16x8*)&W[prow * 64 + pkb + 8];
    __syncthreads();
    f32x4v acc[4];
    #pragma unroll
    for (int c = 0; c < 4; ++c) { acc[c][0] = 0.f; acc[c][1] = 0.f; acc[c][2] = 0.f; acc[c][3] = 0.f; }
    mfma_stage(Xb, Wt, m0, lane, acc, false);
    #pragma unroll
    for (int c4 = 0; c4 < 4; ++c4) {
        #pragma unroll
        for (int r = 0; r < 4; ++r) {
            const int n = nb + m0 + (quad << 2) + r;
            const int col = (c4 << 4) + idx;
            Hb[(size_t)n * 1024 + (l << 6) + col] = f2bf(acc[c4][r]);
        }
    }
}

// ---------------- transpose Hb[n][l][64] -> HbT[n][64][16] ----------------
__global__ __launch_bounds__(256) void k_hbT(const unsigned short* __restrict__ Hb,
    unsigned short* __restrict__ HbT)
{
    const int n = (blockIdx.x << 2) + (threadIdx.x >> 6);
    const int c = threadIdx.x & 63;
    u16x8 a, b;
    #pragma unroll
    for (int l = 0; l < 8; ++l) {
        a[l] = Hb[(size_t)n * 1024 + (l << 6) + c];
        b[l] = Hb[(size_t)n * 1024 + ((l + 8) << 6) + c];
    }
    *(u16x8*)&HbT[(size_t)n * 1024 + c * 16]     = a;
    *(u16x8*)&HbT[(size_t)n * 1024 + c * 16 + 8] = b;
}

// ---------------- lin_out GEMM (MFMA): A fp32 -> H2 bf16 ----------------
__global__ __launch_bounds__(256) void k_lgemm(const float* __restrict__ X,
    const unsigned short* __restrict__ WT, unsigned short* __restrict__ H2b)
{
    __shared__ unsigned short Xb[64 * HS];
    __shared__ unsigned short Wt[64 * HS];
    const int l  = blockIdx.y;
    const int nb = blockIdx.x << 6;
    const int t  = threadIdx.x;
    const int lane = t & 63;
    const int m0   = (t >> 6) << 4;
    const int quad = lane >> 4;
    const int idx  = lane & 15;
    const int prow = t >> 2, pkb = (t & 3) << 4;
    const float* Xp = X + (size_t)l * NC + (size_t)nb * 64;
    #pragma unroll
    for (int k = 0; k < 16; ++k) {
        const int i = t + (k << 8);
        Xb[(i >> 6) * HS + (i & 63)] = f2bf(Xp[i]);
    }
    const unsigned short* W = WT + lmap_rt(l) * 4096;
    *(u16x8*)&Wt[prow * HS + pkb]     = *(const u16x8*)&W[prow * 64 + pkb];
    *(u16x8*)&Wt[prow * HS + pkb + 8] = *(const u16x8*)&W[prow * 64 + pkb + 8];
    __syncthreads();
    f32x4v acc[4];
    #pragma unroll
    for (int c = 0; c < 4; ++c) { acc[c][0] = 0.f; acc[c][1] = 0.f; acc[c][2] = 0.f; acc[c][3] = 0.f; }
    mfma_stage(Xb, Wt, m0, lane, acc, false);
    unsigned short* Op = H2b + (size_t)l * NC + (size_t)nb * 64;
    #pragma unroll
    for (int c4 = 0; c4 < 4; ++c4) {
        #pragma unroll
        for (int r = 0; r < 4; ++r) {
            const int row = m0 + (quad << 2) + r;
            Op[(row << 6) + (c4 << 4) + idx] = f2bf(acc[c4][r]);
        }
    }
}

// ---------------- sc GEMM over element buckets (MFMA): Fb bf16 -> scb bf16 ----------------
__global__ __launch_bounds__(256) void k_sc(const unsigned short* __restrict__ Fb,
    const unsigned short* __restrict__ WscT, const int* __restrict__ perm,
    const int* __restrict__ elem, unsigned short* __restrict__ scb)
{
    __shared__ unsigned short Xb[64 * HS];
    __shared__ unsigned short Wt[64 * HS];
    __shared__ int rows[64];
    const int l  = blockIdx.y;
    const int tb = blockIdx.x << 6;
    const int t  = threadIdx.x;
    if (t < 64) rows[t] = perm[tb + t];
    __syncthreads();
    if (rows[0] < 0) return;
    const int lane = t & 63;
    const int m0   = (t >> 6) << 4;
    const int quad = lane >> 4;
    const int idx  = lane & 15;
    const int prow = t >> 2, pkb = (t & 3) << 4;
    const unsigned short* W = WscT + elem[rows[0]] * 4096;
    *(u16x8*)&Wt[prow * HS + pkb]     = *(const u16x8*)&W[prow * 64 + pkb];
    *(u16x8*)&Wt[prow * HS + pkb + 8] = *(const u16x8*)&W[prow * 64 + pkb + 8];
    {
        const int n = rows[prow];
        u16x8 z;
        #pragma unroll
        for (int j = 0; j < 8; ++j) z[j] = 0;
        u16x8 x0 = z, x1 = z;
        if (n >= 0) {
            const unsigned short* src = Fb + (size_t)l * NC + (size_t)n * 64 + pkb;
            x0 = *(const u16x8*)&src[0];
            x1 = *(const u16x8*)&src[8];
        }
        *(u16x8*)&Xb[prow * HS + pkb]     = x0;
        *(u16x8*)&Xb[prow * HS + pkb + 8] = x1;
    }
    __syncthreads();
    f32x4v acc[4];
    #pragma unroll
    for (int c = 0; c < 4; ++c) { acc[c][0] = 0.f; acc[c][1] = 0.f; acc[c][2] = 0.f; acc[c][3] = 0.f; }
    mfma_stage(Xb, Wt, m0, lane, acc, false);
    #pragma unroll
    for (int c4 = 0; c4 < 4; ++c4) {
        #pragma unroll
        for (int r = 0; r < 4; ++r) {
            const int n = rows[m0 + (quad << 2) + r];
            if (n >= 0) scb[(size_t)l * NC + (size_t)n * 64 + (c4 << 4) + idx] = f2bf(acc[c4][r]);
        }
    }
}

// ---------------- fused edge MLP + aggregation (round-11 proven agg loop) ----------------
__global__ __launch_bounds__(256) void k_edge(const float4* __restrict__ geomv,
    const int* __restrict__ spck, const unsigned short* __restrict__ WT,
    const unsigned short* __restrict__ HbT, const int* __restrict__ roff,
    float* __restrict__ A)
{
    __shared__ unsigned short hbf[64 * HS];
    __shared__ unsigned short wtb[64 * HS];
    __shared__ unsigned short wfull[64 * WS2];
    __shared__ float geos[64 * 4];
    __shared__ int   sps[64];
    __shared__ int   rinfo[2];
    const int t = threadIdx.x;
    const int lane = t & 63;
    const int wid  = t >> 6;
    const int m0   = wid << 4;
    const int quad = lane >> 4;
    const int idx  = lane & 15;
    const int prow = t >> 2, pkb = (t & 3) << 4;
    const int w0 = blockIdx.x << 6;
    const int w1 = w0 + 64;
    if (t == 0) {
        int lo = 0, hi = N - 1;
        while (lo < hi) { const int mid = (lo + hi + 1) >> 1; if (roff[mid] <= w0) lo = mid; else hi = mid - 1; }
        rinfo[0] = lo;
    } else if (t == 1) {
        const int w1m = w0 + 63;
        int lo = 0, hi = N - 1;
        while (lo < hi) { const int mid = (lo + hi + 1) >> 1; if (roff[mid] <= w1m) lo = mid; else hi = mid - 1; }
        rinfo[1] = lo;
    }
    if (t < 64) {
        const float4 g = geomv[w0 + t];
        *(float4*)&geos[t * 4] = g;
        sps[t] = spck[w0 + t];
        const float r = g.w;
        const float u  = r * 0.2f;
        const float u2 = u * u, u5 = u2 * u2 * u;
        const float fc = 1.f - 21.f * u5 + 35.f * u5 * u - 15.f * u5 * u2;
        float pref = 0.63245553f * fc / (r + 1e-9f);
        if (u >= 1.f) pref = 0.f;
        const float piu = 3.14159265358979f * u;
        #pragma unroll
        for (int b = 0; b < 8; ++b) hbf[t * HS + b] = f2bf(__sinf((float)(b + 1) * piu) * pref);
    }
    {
        const int n = t >> 2, k = (t & 3) << 1;
        wtb[n * HS + k]     = WT[n * 8 + k];
        wtb[n * HS + k + 1] = WT[n * 8 + k + 1];
    }
    u16x8 pf0 = *(const u16x8*)&WT[512 + prow * 64 + pkb];
    u16x8 pf1 = *(const u16x8*)&WT[512 + prow * 64 + pkb + 8];
    __syncthreads();
    f32x4v acc[4];
    #pragma unroll
    for (int c = 0; c < 4; ++c) { acc[c][0] = 0.f; acc[c][1] = 0.f; acc[c][2] = 0.f; acc[c][3] = 0.f; }
    mfma_stage(hbf, wtb, m0, lane, acc, true);
    __syncthreads();
    #pragma unroll
    for (int c4 = 0; c4 < 4; ++c4)
        #pragma unroll
        for (int r = 0; r < 4; ++r)
            hbf[(m0 + (quad << 2) + r) * HS + (c4 << 4) + idx] = f2bf(silu(acc[c4][r]));
    *(u16x8*)&wtb[prow * HS + pkb]     = pf0;
    *(u16x8*)&wtb[prow * HS + pkb + 8] = pf1;
    pf0 = *(const u16x8*)&WT[4608 + prow * 64 + pkb];
    pf1 = *(const u16x8*)&WT[4608 + prow * 64 + pkb + 8];
    __syncthreads();
    #pragma unroll
    for (int c = 0; c < 4; ++c) { acc[c][0] = 0.f; acc[c][1] = 0.f; acc[c][2] = 0.f; acc[c][3] = 0.f; }
    mfma_stage(hbf, wtb, m0, lane, acc, false);
    __syncthreads();
    #pragma unroll
    for (int c4 = 0; c4 < 4; ++c4)
        #pragma unroll
        for (int r = 0; r < 4; ++r)
            hbf[(m0 + (quad << 2) + r) * HS + (c4 << 4) + idx] = f2bf(silu(acc[c4][r]));
    *(u16x8*)&wtb[prow * HS + pkb]     = pf0;
    *(u16x8*)&wtb[prow * HS + pkb + 8] = pf1;
    pf0 = *(const u16x8*)&WT[8704 + prow * 64 + pkb];
    pf1 = *(const u16x8*)&WT[8704 + prow * 64 + pkb + 8];
    __syncthreads();
    #pragma unroll
    for (int c = 0; c < 4; ++c) { acc[c][0] = 0.f; acc[c][1] = 0.f; acc[c][2] = 0.f; acc[c][3] = 0.f; }
    mfma_stage(hbf, wtb, m0, lane, acc, false);
    __syncthreads();
    #pragma unroll
    for (int c4 = 0; c4 < 4; ++c4)
        #pragma unroll
        for (int r = 0; r < 4; ++r)
            hbf[(m0 + (quad << 2) + r) * HS + (c4 << 4) + idx] = f2bf(silu(acc[c4][r]));
    *(u16x8*)&wtb[prow * HS + pkb]     = pf0;
    *(u16x8*)&wtb[prow * HS + pkb + 8] = pf1;
    pf0 = *(const u16x8*)&WT[8704 + 4096 + prow * 64 + pkb];
    pf1 = *(const u16x8*)&WT[8704 + 4096 + prow * 64 + pkb + 8];
    __syncthreads();
    for (int cc = 0; cc < 4; ++cc) {
        #pragma unroll
        for (int c = 0; c < 4; ++c) { acc[c][0] = 0.f; acc[c][1] = 0.f; acc[c][2] = 0.f; acc[c][3] = 0.f; }
        mfma_stage(hbf, wtb, m0, lane, acc, false);
        __syncthreads();
        #pragma unroll
        for (int c4 = 0; c4 < 4; ++c4)
            #pragma unroll
            for (int r = 0; r < 4; ++r)
                wfull[(m0 + (quad << 2) + r) * WS2 + (cc << 6) + (c4 << 4) + idx] = f2bf(acc[c4][r]);
        if (cc < 3) {
            *(u16x8*)&wtb[prow * HS + pkb]     = pf0;
            *(u16x8*)&wtb[prow * HS + pkb + 8] = pf1;
            if (cc < 2) {
                pf0 = *(const u16x8*)&WT[8704 + (cc + 2) * 4096 + prow * 64 + pkb];
                pf1 = *(const u16x8*)&WT[8704 + (cc + 2) * 4096 + prow * 64 + pkb + 8];
            }
        }
        __syncthreads();
    }
    const int r0 = rinfo[0], r1 = rinfo[1];
    constexpr int LM[16] = {0,1,1,1,2,2,2,2,2,3,3,3,3,3,3,3};
    for (int r = r0 + wid; r <= r1; r += 4) {
        const int ra = roff[r], rb = roff[r + 1];
        const int ja = ra > w0 ? ra : w0;
        const int jb = rb < w1 ? rb : w1;
        float a16[16];
        #pragma unroll
        for (int l = 0; l < 16; ++l) a16[l] = 0.f;
        if (ja < jb) {
            u16x8 hA0, hB0, hA1, hB1;
            {
                const int s = sps[ja - w0];
                hA0 = *(const u16x8*)&HbT[(size_t)s * 1024 + lane * 16];
                hB0 = *(const u16x8*)&HbT[(size_t)s * 1024 + lane * 16 + 8];
            }
            hA1 = hA0; hB1 = hB0;
            if (ja + 1 < jb) {
                const int s = sps[ja + 1 - w0];
                hA1 = *(const u16x8*)&HbT[(size_t)s * 1024 + lane * 16];
                hB1 = *(const u16x8*)&HbT[(size_t)s * 1024 + lane * 16 + 8];
            }
            for (int j = ja; j < jb; ++j) {
                const int jj = j - w0;
                float hc[16];
                #pragma unroll
                for (int l = 0; l < 8; ++l) { hc[l] = bf2f(hA0[l]); hc[l + 8] = bf2f(hB0[l]); }
                hA0 = hA1; hB0 = hB1;
                if (j + 2 < jb) {
                    const int s = sps[jj + 2];
                    hA1 = *(const u16x8*)&HbT[(size_t)s * 1024 + lane * 16];
                    hB1 = *(const u16x8*)&HbT[(size_t)s * 1024 + lane * 16 + 8];
                }
                const float gr = geos[jj * 4 + 3];
                if (gr >= RMAX) continue;
                const float x = geos[jj * 4], y = geos[jj * 4 + 1], z = geos[jj * 4 + 2];
                const float xx = x * x, yy = y * y, zz = z * z;
                float Y[16];
                Y[0] = 1.f;
                Y[1] = 1.7320508f * x;  Y[2] = 1.7320508f * y;  Y[3] = 1.7320508f * z;
                Y[4] = 3.8729833f * x * y;  Y[5] = 3.8729833f * y * z;
                Y[6] = 0.5f * 2.2360680f * (3.f * zz - 1.f);
                Y[7] = 3.8729833f * x * z;  Y[8] = 0.5f * 3.8729833f * (xx - yy);
                Y[9]  = 2.0916500f * y * (3.f * xx - yy);
                Y[10] = 10.2469508f * x * y * z;
                Y[11] = 1.6201852f * y * (5.f * zz - 1.f);
                Y[12] = 0.5f * 2.6457513f * z * (5.f * zz - 3.f);
                Y[13] = 1.6201852f * x * (5.f * zz - 1.f);
                Y[14] = 0.5f * 10.2469508f * z * (xx - yy);
                Y[15] = 2.0916500f * x * (xx - 3.f * yy);
                float se = 0.f;
                #pragma unroll
                for (int l = 0; l < 16; ++l) se += hc[l] * Y[l];
                se *= 0.0625f;
                const ushort4 wq = *(const ushort4*)&wfull[jj * WS2 + (lane << 2)];
                const float wl[4] = { bf2f(wq.x) * se, bf2f(wq.y) * se, bf2f(wq.z) * se, bf2f(wq.w) * se };
                #pragma unroll
                for (int l = 0; l < 16; ++l) a16[l] += wl[LM[l]] * Y[l];
            }
        }
        float* Ap = A + (size_t)r * 64 + lane;
        if (ra >= w0 && rb <= w1) {
            #pragma unroll
            for (int l = 0; l < 16; ++l) Ap[(size_t)l * NC] = a16[l];
        } else {
            #pragma unroll
            for (int l = 0; l < 16; ++l) atomicAdd(&Ap[(size_t)l * NC], a16[l]);
        }
    }
}

// ---------------- s1[n][c] = sum_l H2[l][n][c]^2 (bf16 in) ----------------
__global__ __launch_bounds__(256) void k_s1(const unsigned short* __restrict__ H2b, float* __restrict__ s1)
{
    const int i = blockIdx.x * 256 + threadIdx.x;
    if (i < NC) {
        float s = 0.f;
        #pragma unroll
        for (int l = 0; l < 16; ++l) { const float a = bf2f(H2b[(size_t)l * NC + i]); s += a * a; }
        s1[i] = s;
    }
}

// ---------------- out = sum_p (A'*s1^p)@Wp_p + sc -> Fb  (MFMA, bf16 state) ----------------
__global__ __launch_bounds__(256) void k_out(const unsigned short* __restrict__ H2b,
    const float* __restrict__ s1, const unsigned short* __restrict__ WpT,
    const unsigned short* __restrict__ scb, unsigned short* __restrict__ Fb)
{
    __shared__ unsigned short Xb[64 * HS];
    __shared__ unsigned short Wt[64 * HS];
    const int l  = blockIdx.y;
    const int nb = blockIdx.x << 6;
    const int t  = threadIdx.x;
    const int lane = t & 63;
    const int m0   = (t >> 6) << 4;
    const int quad = lane >> 4;
    const int idx  = lane & 15;
    const int prow = t >> 2, pkb = (t & 3) << 4;
    const unsigned short* Xp = H2b + (size_t)l * NC + (size_t)nb * 64;
    float av[16], sv[16];
    {
        const u16x8 x0 = *(const u16x8*)&Xp[prow * 64 + pkb];
        const u16x8 x1 = *(const u16x8*)&Xp[prow * 64 + pkb + 8];
        #pragma unroll
        for (int j = 0; j < 8; ++j) { av[j] = bf2f(x0[j]); av[8 + j] = bf2f(x1[j]); }
        #pragma unroll
        for (int j = 0; j < 4; ++j) {
            const float4 s4 = *(const float4*)&s1[(nb + prow) * 64 + pkb + (j << 2)];
            sv[j * 4] = s4.x; sv[j * 4 + 1] = s4.y; sv[j * 4 + 2] = s4.z; sv[j * 4 + 3] = s4.w;
        }
    }
    f32x4v acc[4];
    #pragma unroll
    for (int c = 0; c < 4; ++c) { acc[c][0] = 0.f; acc[c][1] = 0.f; acc[c][2] = 0.f; acc[c][3] = 0.f; }
    for (int p = 0; p < 3; ++p) {
        u16x8 x0, x1;
        #pragma unroll
        for (int j = 0; j < 8; ++j) { x0[j] = f2bf(av[j]); x1[j] = f2bf(av[8 + j]); }
        *(u16x8*)&Xb[prow * HS + pkb]     = x0;
        *(u16x8*)&Xb[prow * HS + pkb + 8] = x1;
        #pragma unroll
        for (int k = 0; k < 16; ++k) av[k] *= sv[k];
        *(u16x8*)&Wt[prow * HS + pkb]     = *(const u16x8*)&WpT[p * 4096 + prow * 64 + pkb];
        *(u16x8*)&Wt[prow * HS + pkb + 8] = *(const u16x8*)&WpT[p * 4096 + prow * 64 + pkb + 8];
        __syncthreads();
        mfma_stage(Xb, Wt, m0, lane, acc, false);
        __syncthreads();
    }
    #pragma unroll
    for (int c4 = 0; c4 < 4; ++c4) {
        #pragma unroll
        for (int r = 0; r < 4; ++r) {
            const int row = m0 + (quad << 2) + r;
            const int col = (c4 << 4) + idx;
            const size_t id = (size_t)l * NC + (size_t)(nb + row) * 64 + col;
            Fb[id] = f2bf(acc[c4][r] + bf2f(scb[id]));
        }
    }
}

// ---------------- readout (bf16 F) ----------------
__global__ __launch_bounds__(256) void k_read(const unsigned short* __restrict__ Fb,
    const float* __restrict__ q, const int* __restrict__ batch,
    const float* __restrict__ Wr0, const float* __restrict__ Wa,
    const float* __restrict__ Wb, const float* __restrict__ Wq,
    float* __restrict__ acc, int last)
{
    __shared__ float sred[G];
    if (threadIdx.x < G) sred[threadIdx.x] = 0.f;
    __syncthreads();
    const int n = blockIdx.x * 256 + threadIdx.x;
    if (n < N) {
        float a16[16];
        #pragma unroll
        for (int j = 0; j < 16; ++j) a16[j] = 0.f;
        float ar = 0.f, aq = 0.f;
        const unsigned short* f = Fb + (size_t)n * 64;
        for (int c = 0; c < 64; ++c) {
            const float fv = bf2f(f[c]);
            aq += fv * Wq[c];
            if (last) {
                #pragma unroll
                for (int j = 0; j < 16; ++j) a16[j] += fv * Wa[c * 16 + j];
            } else ar += fv * Wr0[c];
        }
        float en;
        if (last) {
            en = 0.f;
            #pragma unroll
            for (int j = 0; j < 16; ++j) en += silu(a16[j]) * Wb[j];
        } else en = ar;
        en += q[n] * aq;
        atomicAdd(&sred[batch[n]], en);
    }
    __syncthreads();
    if (threadIdx.x < G) atomicAdd(&acc[threadIdx.x * 5], sred[threadIdx.x]);
}

// ---------------- Ewald (kvec computed inline) ----------------
__global__ __launch_bounds__(256) void k_phase(const float* __restrict__ pos,
    const float* __restrict__ q, const float* __restrict__ rcell,
    float* __restrict__ Sr, float* __restrict__ Si)
{
    __shared__ float kvs[38 * 3];
    __shared__ float srs[38], sis[38];
    const int g = blockIdx.z, kc = blockIdx.x, ncb = blockIdx.y;
    const int kbase = kc * 38;
    if (threadIdx.x < 38 * 3) {
        const int j = threadIdx.x / 3, i = threadIdx.x % 3;
        const int k = kbase + j;
        const int kk = k + (k >= 171 ? 1 : 0);
        const int a = kk / 49 - 3, b = (kk / 7) % 7 - 3, c = kk % 7 - 3;
        const float* rc = rcell + g * 9;
        kvs[threadIdx.x] = 6.283185307f * ((float)a * rc[0 + i] + (float)b * rc[3 + i] + (float)c * rc[6 + i]);
    }
    if (threadIdx.x < 38) { srs[threadIdx.x] = 0.f; sis[threadIdx.x] = 0.f; }
    __syncthreads();
    const int t = threadIdx.x;
    float px = 0.f, py = 0.f, pz = 0.f, qn = 0.f;
    if (t < 250) {
        const int n = g * NGR + ncb * 250 + t;
        px = pos[n * 3]; py = pos[n * 3 + 1]; pz = pos[n * 3 + 2]; qn = q[n];
    }
    const int lane = t & 63;
    for (int j = 0; j < 38; ++j) {
        const float ph = px * kvs[j * 3] + py * kvs[j * 3 + 1] + pz * kvs[j * 3 + 2];
        float sv, cv;
        __sincosf(ph, &sv, &cv);
        float vr = qn * cv, vi = qn * sv;
        #pragma unroll
        for (int o = 32; o > 0; o >>= 1) { vr += __shfl_down(vr, o, 64); vi += __shfl_down(vi, o, 64); }
        if (lane == 0) { atomicAdd(&srs[j], vr); atomicAdd(&sis[j], vi); }
    }
    __syncthreads();
    if (t < 38) {
        atomicAdd(&Sr[g * NK + kbase + t], srs[t]);
        atomicAdd(&Si[g * NK + kbase + t], sis[t]);
    }
}

__global__ __launch_bounds__(512) void k_final(const float* __restrict__ rcell,
    const float* __restrict__ Sr, const float* __restrict__ Si,
    const float* __restrict__ vol, const float* __restrict__ acc,
    float* __restrict__ out)
{
    __shared__ float red[512];
    const int g = blockIdx.x, t = threadIdx.x;
    float v = 0.f;
    if (t < NK) {
        const int kk = t + (t >= 171 ? 1 : 0);
        const int a = kk / 49 - 3, b = (kk / 7) % 7 - 3, c = kk % 7 - 3;
        const float* rc = rcell + g * 9;
        float k2v = 0.f;
        #pragma unroll
        for (int i = 0; i < 3; ++i) {
            const float kv = 6.283185307f * ((float)a * rc[0 + i] + (float)b * rc[3 + i] + (float)c * rc[6 + i]);
            k2v += kv * kv;
        }
        const float sr = Sr[g * NK + t], si = Si[g * NK + t];
        v = __expf(-0.5f * k2v) * (sr * sr + si * si) / k2v;
    }
    red[t] = v;
    __syncthreads();
    for (int s2 = 256; s2 > 0; s2 >>= 1) {
        if (t < s2) red[t] += red[t + s2];
        __syncthreads();
    }
    if (t == 0) {
        const float Ees = 6.283185307f / vol[g] * red[0];
        out[g]     = acc[g * 5 + 0] + Ees;
        out[4 + g] = acc[g * 5 + 1];
        out[8 + g * 3 + 0] = acc[g * 5 + 2];
        out[8 + g * 3 + 1] = acc[g * 5 + 3];
        out[8 + g * 3 + 2] = acc[g * 5 + 4];
    }
}

extern "C" void kernel_launch(void* const* d_in, const int* in_sizes, int n_in,
                              void* d_out, int out_size, void* d_ws, size_t ws_size,
                              hipStream_t stream)
{
    const float* na    = (const float*)d_in[0];
    const float* pos   = (const float*)d_in[1];
    const float* shif  = (const float*)d_in[2];
    const float* q     = (const float*)d_in[3];
    const float* rcell = (const float*)d_in[5];
    const float* vol   = (const float*)d_in[6];
    const int*   ei    = (const int*)d_in[7];
    const int*   batch = (const int*)d_in[8];
    const float* embW  = (const float*)d_in[9];
    const float* qcoef = (const float*)d_in[10];
    const float* rW1   = (const float*)d_in[11];
    const float* rW2   = (const float*)d_in[12];
    const float* rW3   = (const float*)d_in[13];
    const float* rW4   = (const float*)d_in[14];
    const float* lup   = (const float*)d_in[15];
    const float* lout  = (const float*)d_in[16];
    const float* Wsc   = (const float*)d_in[17];
    const float* Wp    = (const float*)d_in[18];
    const float* Wr0   = (const float*)d_in[19];
    const float* Wa    = (const float*)d_in[20];
    const float* Wb    = (const float*)d_in[21];
    const float* Wq    = (const float*)d_in[22];
    const float* aE    = (const float*)d_in[23];
    float* out = (float*)d_out;

    float* wsf  = (float*)d_ws;
    unsigned short* Fb = (unsigned short*)wsf;           // bf16 [16][N][64]
    float* A    = wsf + 8192000;        // [16][N][64] fp32 (agg out); later aliased as scb bf16
    unsigned short* scb = (unsigned short*)A;            // bf16 [16][N][64]
    float* R    = A + 8192000;
    unsigned short* H2b   = (unsigned short*)R;              // bf16 [16][N][64]
    unsigned short* HbT   = (unsigned short*)R;              // bf16 [N][64][16]
    unsigned short* Hbtmp = (unsigned short*)(R + 4096000);  // bf16 [N][16][64] (transient)
    float* s1   = R + 20480000;         // [N][64]
    float* kvec = s1 + 512000;          // (unused)
    float* k2   = kvec + 4104;          // (unused)
    float* Sr   = k2 + 1368;
    float* Si   = Sr + 1368;
    float* acc  = Si + 1368;            // [G][5]
    int*   elem = (int*)(acc + 32);     // [N]
    int*   perm = elem + 8000;          // [8640]
    int*   counts = perm + 8640;        // [16]
    int*   cursor = counts + 16;        // [16]
    int*   offs   = cursor + 16;        // [16]
    int*   roff   = offs + 16;          // [N+1]
    int*   cnt    = roff + 8001;        // [N]
    int*   cur    = cnt + 8000;         // [N]
    int*   elist  = cur + 8000;         // [E]
    unsigned short* WTb = (unsigned short*)(((uintptr_t)(elist + E) + 31) & ~(uintptr_t)31); // [2*WT_T]
    unsigned short* WpT = WTb + 2 * WT_T;                // [24576]
    float4* geomv = (float4*)(WpT + 24576);              // [E]
    int*    spck  = (int*)(geomv + E);                   // [E]
    unsigned short* WlupT  = (unsigned short*)(spck + E); // [32768]
    unsigned short* WloutT = WlupT + 32768;               // [32768]
    unsigned short* WscT   = WloutT + 32768;              // [81920]

    hipMemsetAsync(Fb, 0, 8192000 * sizeof(unsigned short), stream);
    hipMemsetAsync(Sr, 0, (1368 * 2 + 32) * sizeof(float), stream);
    hipMemsetAsync(perm, 0xFF, 8640 * sizeof(int), stream);
    hipMemsetAsync(counts, 0, 32 * sizeof(int), stream);
    hipMemsetAsync(cnt, 0, 16000 * sizeof(int), stream);

    k_init<<<32, 256, 0, stream>>>(na, q, pos, batch, aE, elem, counts, acc);
    k_feat0<<<2000, 256, 0, stream>>>(elem, embW, Fb);
    k_gcnt<<<500, 256, 0, stream>>>(ei, cnt);
    k_goff<<<1, 1024, 0, stream>>>(cnt, roff, counts, offs);
    k_scatter<<<32, 256, 0, stream>>>(elem, offs, cursor, perm);
    k_gscat<<<500, 256, 0, stream>>>(ei, roff, cur, elist);
    k_geom<<<500, 256, 0, stream>>>(pos, shif, ei, elist, geomv, spck);
    k_wprep_all<<<868, 256, 0, stream>>>(rW1, rW2, rW3, rW4, Wp, lup, lout, Wsc,
                                         WTb, WpT, WlupT, WloutT, WscT);
    k_phase<<<dim3(9, 8, G), 256, 0, stream>>>(pos, q, rcell, Sr, Si);

    for (int t = 0; t < 2; ++t) {
        k_lgemm_hb<<<dim3(125, 16), 256, 0, stream>>>(Fb, q, qcoef + t * 64, WlupT + t * 16384, Hbtmp);
        k_hbT<<<2000, 256, 0, stream>>>(Hbtmp, HbT);
        hipMemsetAsync(A, 0, 8192000 * sizeof(float), stream);
        k_edge<<<2000, 256, 0, stream>>>(geomv, spck, WTb + t * WT_T, HbT, roff, A);
        k_lgemm<<<dim3(125, 16), 256, 0, stream>>>(A, WloutT + t * 16384, H2b);
        k_s1<<<2000, 256, 0, stream>>>(H2b, s1);
        k_sc<<<dim3(135, 16), 256, 0, stream>>>(Fb, WscT + t * 40960, perm, elem, scb);
        k_out<<<dim3(125, 16), 256, 0, stream>>>(H2b, s1, WpT + t * 12288, scb, Fb);
        k_read<<<32, 256, 0, stream>>>(Fb, q, batch, Wr0, Wa, Wb, Wq + t * 64, acc, t == 1);
    }
    k_final<<<G, 512, 0, stream>>>(rcell, Sr, Si, vol, acc, out);
}